// Round 9
// baseline (175.411 us; speedup 1.0000x reference)
//
#include <hip/hip_runtime.h>
#include <math.h>

#define NODES   16384
#define NGRAPH  1024
#define EDGES   245760
#define EPG     240
#define FDIM    256

#define OUT_MEAN  0
#define OUT_STD   24576
#define OUT_SCANS 49152
#define OUT_RECON 376832

typedef __attribute__((ext_vector_type(4))) short bf16x4;
typedef __attribute__((ext_vector_type(8))) short bf16x8;
typedef __attribute__((ext_vector_type(4))) float f32x4;

static __device__ __forceinline__ float lrelu02(float v){ return v > 0.f ? v : 0.2f*v; }

static __device__ __forceinline__ unsigned short f2bf(float f){
    unsigned u = __float_as_uint(f);
    u = (u + 0x7FFFu + ((u >> 16) & 1u)) >> 16;
    return (unsigned short)u;
}
static __device__ __forceinline__ float bf2f(unsigned short h){
    return __uint_as_float(((unsigned)h) << 16);
}

// ============ prep kernel: wtrans + fc1 transpose + ea partials + lidar =====
__global__ __launch_bounds__(256) void prep_kernel(
    const float* __restrict__ x,  const float* __restrict__ ea,
    const float* __restrict__ W2, const float* __restrict__ W3,
    const float* __restrict__ F1,
    const float* __restrict__ w1, const float* __restrict__ b1,
    const float* __restrict__ w2, const float* __restrict__ b2,
    const float* __restrict__ wl, const float* __restrict__ bl,
    const float* __restrict__ dw1, const float* __restrict__ db1,
    const float* __restrict__ dw2, const float* __restrict__ db2,
    unsigned short* __restrict__ T2, unsigned short* __restrict__ T3,
    unsigned short* __restrict__ T1, float* __restrict__ partial,
    float* __restrict__ out)
{
    __shared__ float red[256];
    __shared__ float sc[8][25];
    __shared__ float pooled[8][160];
    __shared__ float hid_lds[8][32];

    const int b = blockIdx.x;
    const int tid = threadIdx.x;

    if (b < 512) {
        const float* W = (b < 256) ? W2 : W3;
        unsigned short* T = (b < 256) ? T2 : T3;
        const int n = b & 255;
        T[n * 256 + tid] = f2bf(W[tid * 256 + n]);
        return;
    }
    if (b < 640) {
        const int o = b - 512;
        const int k0 = tid * 2;
        T1[o * 512 + k0]     = f2bf(F1[o * 515 + k0]);
        T1[o * 512 + k0 + 1] = f2bf(F1[o * 515 + k0 + 1]);
        return;
    }
    if (b < 896) {
        const int base = (b - 640) * 960;
        float s = 0.f;
        for (int i = tid; i < 960; i += 256) s += ea[base + i];
        red[tid] = s; __syncthreads();
        for (int off = 128; off > 0; off >>= 1) {
            if (tid < off) red[tid] += red[tid + off];
            __syncthreads();
        }
        if (tid == 0) partial[b - 640] = red[0];
        return;
    }

    // ---- lidar (verified body) ----
    const int lane = tid & 31;
    const int nl   = tid >> 5;
    const int n    = (b - 896) * 8 + nl;

    if (lane < 20) {
        const float v = x[n * 29 + lane];
        sc[nl][lane + 2] = v;
        out[OUT_SCANS + n * 20 + lane] = v;
    } else if (lane < 25) {
        const int pads[5] = {0, 1, 22, 23, 24};
        sc[nl][pads[lane - 20]] = 0.f;
    }
    __syncthreads();

    {
        const int ic = lane & 15;
        const int hi = lane >> 4;
        float w1r[5];
#pragma unroll
        for (int k = 0; k < 5; ++k) w1r[k] = w1[ic * 5 + k];
        const float b1r = b1[ic];
#pragma unroll
        for (int q = 0; q < 5; ++q) {
            const int u  = 2 * q + hi;
            const int p0 = 2 * u;
            float a = b1r, bb = b1r;
#pragma unroll
            for (int k = 0; k < 5; ++k) {
                a  += sc[nl][p0 + k] * w1r[k];
                bb += sc[nl][p0 + 1 + k] * w1r[k];
            }
            pooled[nl][u * 16 + ic] = fmaxf(fmaxf(a, bb), 0.f);
        }
    }
    __syncthreads();

    float macc = 0.f;
    {
        float wreg[48];
#pragma unroll
        for (int i = 0; i < 12; ++i) {
            const float4 v4 = *(const float4*)&w2[lane * 48 + i * 4];
            wreg[i * 4 + 0] = v4.x; wreg[i * 4 + 1] = v4.y;
            wreg[i * 4 + 2] = v4.z; wreg[i * 4 + 3] = v4.w;
        }
        const float b2r = b2[lane];
        float pc[3][16];
#pragma unroll
        for (int i = 0; i < 4; ++i) {
            const float4 v0 = *(const float4*)&pooled[nl][0 * 16 + i * 4];
            const float4 v1 = *(const float4*)&pooled[nl][1 * 16 + i * 4];
            pc[0][i * 4 + 0] = v0.x; pc[0][i * 4 + 1] = v0.y; pc[0][i * 4 + 2] = v0.z; pc[0][i * 4 + 3] = v0.w;
            pc[1][i * 4 + 0] = v1.x; pc[1][i * 4 + 1] = v1.y; pc[1][i * 4 + 2] = v1.z; pc[1][i * 4 + 3] = v1.w;
            pc[2][i * 4 + 0] = 0.f;  pc[2][i * 4 + 1] = 0.f;  pc[2][i * 4 + 2] = 0.f;  pc[2][i * 4 + 3] = 0.f;
        }
#pragma unroll
        for (int t = 0; t < 10; ++t) {
            const int prev = (t + 2) % 3, cur = t % 3, nxt = (t + 1) % 3;
            if (t >= 1) {
                if (t + 1 <= 9) {
#pragma unroll
                    for (int i = 0; i < 4; ++i) {
                        const float4 v4 = *(const float4*)&pooled[nl][(t + 1) * 16 + i * 4];
                        pc[nxt][i * 4 + 0] = v4.x; pc[nxt][i * 4 + 1] = v4.y;
                        pc[nxt][i * 4 + 2] = v4.z; pc[nxt][i * 4 + 3] = v4.w;
                    }
                } else {
#pragma unroll
                    for (int ic = 0; ic < 16; ++ic) pc[nxt][ic] = 0.f;
                }
            }
            float v = b2r;
#pragma unroll
            for (int ic = 0; ic < 16; ++ic) {
                v += pc[prev][ic] * wreg[ic * 3 + 0]
                   + pc[cur][ic]  * wreg[ic * 3 + 1]
                   + pc[nxt][ic]  * wreg[ic * 3 + 2];
            }
            macc += fmaxf(v, 0.f);
        }
    }

    const float feat = macc * 0.1f;
    float z[5];
#pragma unroll
    for (int j = 0; j < 5; ++j) {
        float p = feat * wl[j * 32 + lane];
        p += __shfl_xor(p, 1);
        p += __shfl_xor(p, 2);
        p += __shfl_xor(p, 4);
        p += __shfl_xor(p, 8);
        p += __shfl_xor(p, 16);
        z[j] = fmaxf(bl[j] + p, 0.f);
    }
    float hv = db1[lane];
#pragma unroll
    for (int j = 0; j < 5; ++j) hv += z[j] * dw1[lane * 5 + j];
    hid_lds[nl][lane] = fmaxf(hv, 0.f);
    __syncthreads();

    if (lane < 20) {
        float acc = db2[lane];
#pragma unroll
        for (int k = 0; k < 32; ++k) acc += hid_lds[nl][k] * dw2[lane * 32 + k];
        out[OUT_RECON + n * 20 + lane] = acc;
    }
}

// ============ fused per-graph kernel: GAT1 -> GAT2 -> GAT3 -> heads =========
// Block = graph. LDS ~30KB (5 blocks/CU). h between layers: bf16 swizzled
// MFMA A-tile (hsb). Aggregate = MFMA with coef as A ([h][d][s] bf16) and
// xw as B taken DIRECTLY from the GEMM's D-registers (layouts match).
__global__ __launch_bounds__(256) void graph_kernel(
    const float* __restrict__ x,   const float* __restrict__ ea,
    const float* __restrict__ partial,
    const float* __restrict__ g1_W,
    const float* __restrict__ g1_as, const float* __restrict__ g1_ad,
    const float* __restrict__ g1_We, const float* __restrict__ g1_ae,
    const float* __restrict__ g1_b,
    const unsigned short* __restrict__ WT2,
    const float* __restrict__ g2_as, const float* __restrict__ g2_ad,
    const float* __restrict__ g2_We, const float* __restrict__ g2_ae,
    const float* __restrict__ g2_b,
    const unsigned short* __restrict__ WT3,
    const float* __restrict__ g3_as, const float* __restrict__ g3_ad,
    const float* __restrict__ g3_We, const float* __restrict__ g3_ae,
    const float* __restrict__ g3_b,
    const unsigned short* __restrict__ FT1,
    const float* __restrict__ fc1W, const float* __restrict__ fc1b,
    const float* __restrict__ fc2W, const float* __restrict__ fc2b,
    float* __restrict__ out)
{
    __shared__ char  hsb[8192]   __attribute__((aligned(16)));
    __shared__ unsigned short xwb[16][256];                       // bf16 xw, linear
    __shared__ unsigned short coefb[8][16][20] __attribute__((aligned(8))); // [h][d][s] pad
    __shared__ float sals[16][8], sald[16][8];
    __shared__ float sasrc[256], sadst[256], sS[8];
    __shared__ float hs6[16][6];
    __shared__ float lash[8][3];
    __shared__ float hidn[8][128];
    __shared__ unsigned short gembb[256];
    __shared__ float red4[4];
    __shared__ float eamean_s;

    const int tid = threadIdx.x, g = blockIdx.x;
    const int lane = tid & 63, w = tid >> 6;
    const int arow = lane & 15, kg = lane >> 4;

    // --- edge-attr mean from partials ---
    {
        float pv = partial[tid];
        pv += __shfl_down(pv, 32);
        pv += __shfl_down(pv, 16);
        pv += __shfl_down(pv, 8);
        pv += __shfl_down(pv, 4);
        pv += __shfl_down(pv, 2);
        pv += __shfl_down(pv, 1);
        if ((tid & 63) == 0) red4[tid >> 6] = pv;
    }
    if (tid < 96) { int i = tid / 6, k = tid % 6; hs6[i][k] = x[(g * 16 + i) * 29 + 20 + k]; }
    if (tid >= 128 && tid < 152) {
        int t = tid - 128, a = t / 3, j = t % 3;
        lash[a][j] = x[(g * 16 + a) * 29 + 26 + j];
    }
    sasrc[tid] = g1_as[tid];
    sadst[tid] = g1_ad[tid];
    if (tid < 8) {
        float s = 0.f;
        for (int c = 0; c < 32; ++c) s += g1_We[tid * 32 + c] * g1_ae[tid * 32 + c];
        sS[tid] = s;
    }
    __syncthreads();
    if (tid == 0) eamean_s = (red4[0] + red4[1] + red4[2] + red4[3]) * (1.f / (float)EDGES);

    // ===== layer 1: GEMM K=6 (VALU), acc kept in regs =====
    float acc1[16];
    {
#pragma unroll
        for (int i = 0; i < 16; ++i) acc1[i] = 0.f;
#pragma unroll
        for (int k = 0; k < 6; ++k) {
            float wv = g1_W[k * 256 + tid];
#pragma unroll
            for (int i = 0; i < 16; ++i) acc1[i] += hs6[i][k] * wv;
        }
#pragma unroll
        for (int i = 0; i < 16; ++i) xwb[i][tid] = f2bf(acc1[i]);
    }
    __syncthreads();

    // --- attention dots (256 threads: node x head x {src,dst}) ---
    {
        const int di = tid >> 4;
        const int dh = (tid >> 1) & 7;
        const float* av = (tid & 1) ? sadst : sasrc;
        const unsigned short* xr = &xwb[di][dh * 32];
        float s = 0.f;
#pragma unroll
        for (int c = 0; c < 32; ++c) s += bf2f(xr[c]) * av[dh * 32 + c];
        if (tid & 1) sald[di][dh] = s; else sals[di][dh] = s;
    }
    __syncthreads();
    // --- softmax -> coefb[h][d][s] bf16 (L1: no self loop) ---
    if (tid < 128) {
        const int d = tid >> 3, h = tid & 7;
        const float S = sS[h];
        const float aldv = sald[d][h];
        float alf[16];
        float m = -1e30f;
#pragma unroll
        for (int s = 0; s < 16; ++s) {
            float a;
            if (s == d) a = -1e30f;
            else {
                const int el = s * 15 + d - (d > s ? 1 : 0);
                a = lrelu02(sals[s][h] + aldv + ea[g * EPG + el] * S);
            }
            alf[s] = a;
            m = fmaxf(m, a);
        }
        float sum = 0.f;
#pragma unroll
        for (int s = 0; s < 16; ++s) { alf[s] = expf(alf[s] - m); sum += alf[s]; }
        const float r = 1.f / (sum + 1e-16f);
#pragma unroll
        for (int s = 0; s < 16; ++s) coefb[h][d][s] = f2bf(alf[s] * r);
    }
    __syncthreads();
    // --- L1 aggregate (VALU: coefb bf16 x acc1 regs) -> hsb ---
    {
        const int h = tid >> 5;
        const float b = g1_b[tid];
#pragma unroll
        for (int d = 0; d < 16; ++d) {
            float od = b;
#pragma unroll
            for (int s4 = 0; s4 < 4; ++s4) {
                const bf16x4 cv = *(const bf16x4*)((const char*)coefb + h * 640 + d * 40 + s4 * 8);
                od += bf2f((unsigned short)cv[0]) * acc1[s4 * 4 + 0]
                    + bf2f((unsigned short)cv[1]) * acc1[s4 * 4 + 1]
                    + bf2f((unsigned short)cv[2]) * acc1[s4 * 4 + 2]
                    + bf2f((unsigned short)cv[3]) * acc1[s4 * 4 + 3];
            }
            *(unsigned short*)(hsb + ((d * 512 + tid * 2) ^ ((d & 7) << 4))) = f2bf(fmaxf(od, 0.f));
        }
    }
    __syncthreads();

    // ===== layers 2 and 3 =====
#pragma unroll 1
    for (int ly = 0; ly < 2; ++ly) {
        const unsigned short* WT = ly ? WT3 : WT2;
        const float* as_ = ly ? g3_as : g2_as;
        const float* ad_ = ly ? g3_ad : g2_ad;
        const float* We_ = ly ? g3_We : g2_We;
        const float* ae_ = ly ? g3_ae : g2_ae;
        const float* bi_ = ly ? g3_b  : g2_b;

        sasrc[tid] = as_[tid];
        sadst[tid] = ad_[tid];
        if (tid < 8) {
            float s = 0.f;
            for (int c = 0; c < 32; ++c) s += We_[tid * 32 + c] * ae_[tid * 32 + c];
            sS[tid] = s;
        }
        // --- MFMA GEMM: xw = h @ W ; keep bf16 D-regs for aggregate B ---
        bf16x4 bfrag[4];
        {
            f32x4 acc[4];
#pragma unroll
            for (int nt = 0; nt < 4; ++nt) acc[nt] = (f32x4){0.f, 0.f, 0.f, 0.f};
            const int aswz = (arow & 7) << 4;
            const char* wt = (const char*)WT;
            for (int kk = 0; kk < 8; ++kk) {
                const int ab = arow * 512 + kk * 64 + kg * 8;
                const bf16x4 alo = *(const bf16x4*)(hsb + (ab ^ aswz));
                const bf16x4 ahi = *(const bf16x4*)(hsb + ((ab + 32) ^ aswz));
                const bf16x8 afrag = (bf16x8){alo[0], alo[1], alo[2], alo[3],
                                              ahi[0], ahi[1], ahi[2], ahi[3]};
#pragma unroll
                for (int nt = 0; nt < 4; ++nt) {
                    const int ncol = w * 64 + nt * 16 + arow;
                    const char* bp = wt + ncol * 512 + kk * 64 + kg * 8;
                    const bf16x4 blo = *(const bf16x4*)(bp);
                    const bf16x4 bhi = *(const bf16x4*)(bp + 32);
                    const bf16x8 bfr = (bf16x8){blo[0], blo[1], blo[2], blo[3],
                                                bhi[0], bhi[1], bhi[2], bhi[3]};
                    acc[nt] = __builtin_amdgcn_mfma_f32_16x16x32_bf16(afrag, bfr, acc[nt], 0, 0, 0);
                }
            }
            // D rows kg*4+r at col w*64+nt*16+arow -> xwb + bfrag
#pragma unroll
            for (int nt = 0; nt < 4; ++nt) {
                const int c2 = w * 64 + nt * 16 + arow;
                unsigned short h0 = f2bf(acc[nt][0]);
                unsigned short h1 = f2bf(acc[nt][1]);
                unsigned short h2 = f2bf(acc[nt][2]);
                unsigned short h3 = f2bf(acc[nt][3]);
                bfrag[nt] = (bf16x4){(short)h0, (short)h1, (short)h2, (short)h3};
                xwb[kg * 4 + 0][c2] = h0;
                xwb[kg * 4 + 1][c2] = h1;
                xwb[kg * 4 + 2][c2] = h2;
                xwb[kg * 4 + 3][c2] = h3;
            }
        }
        __syncthreads();

        // --- attention dots (256 threads, bf16 xw) ---
        {
            const int di = tid >> 4;
            const int dh = (tid >> 1) & 7;
            const float* av = (tid & 1) ? sadst : sasrc;
            const unsigned short* xr = &xwb[di][dh * 32];
            float s = 0.f;
#pragma unroll
            for (int c = 0; c < 32; ++c) s += bf2f(xr[c]) * av[dh * 32 + c];
            if (tid & 1) sald[di][dh] = s; else sals[di][dh] = s;
        }
        __syncthreads();
        // --- softmax -> coefb (self loop with eamean) ---
        if (tid < 128) {
            const int d = tid >> 3, h = tid & 7;
            const float S = sS[h];
            const float aldv = sald[d][h];
            float alf[16];
            float m = -1e30f;
#pragma unroll
            for (int s = 0; s < 16; ++s) {
                float a;
                if (s == d) a = lrelu02(sals[s][h] + aldv + eamean_s * S);
                else {
                    const int el = s * 15 + d - (d > s ? 1 : 0);
                    a = lrelu02(sals[s][h] + aldv + ea[g * EPG + el] * S);
                }
                alf[s] = a;
                m = fmaxf(m, a);
            }
            float sum = 0.f;
#pragma unroll
            for (int s = 0; s < 16; ++s) { alf[s] = expf(alf[s] - m); sum += alf[s]; }
            const float r = 1.f / (sum + 1e-16f);
#pragma unroll
            for (int s = 0; s < 16; ++s) coefb[h][d][s] = f2bf(alf[s] * r);
        }
        __syncthreads();
        // --- aggregate via MFMA: A=coefb (K=16 in lo half), B=bfrag regs ---
        {
#pragma unroll
            for (int nt = 0; nt < 4; ++nt) {
                const int h = (w * 2) + (nt >> 1);
                const bf16x4 alo = *(const bf16x4*)((const char*)coefb + h * 640 + arow * 40 + kg * 8);
                const bf16x8 afrag = (bf16x8){alo[0], alo[1], alo[2], alo[3], 0, 0, 0, 0};
                const bf16x8 bfr   = (bf16x8){bfrag[nt][0], bfrag[nt][1], bfrag[nt][2], bfrag[nt][3],
                                              0, 0, 0, 0};
                f32x4 hacc = __builtin_amdgcn_mfma_f32_16x16x32_bf16(
                                 afrag, bfr, (f32x4){0.f, 0.f, 0.f, 0.f}, 0, 0, 0);
                const int c2 = w * 64 + nt * 16 + arow;
                const float b = bi_[c2];
                float p = 0.f;
#pragma unroll
                for (int r = 0; r < 4; ++r) {
                    const float hv = fmaxf(hacc[r] + b, 0.f);
                    p += hv;
                    const int d = kg * 4 + r;
                    *(unsigned short*)(hsb + ((d * 512 + c2 * 2) ^ ((d & 7) << 4))) = f2bf(hv);
                }
                if (ly == 1) {
                    p += __shfl_xor(p, 16);
                    p += __shfl_xor(p, 32);
                    if (kg == 0) gembb[c2] = f2bf(p * (1.f / 16.f));
                }
            }
        }
        __syncthreads();
    }

    // ===== heads fc1 via MFMA: A = [hsb | gembb-broadcast], B = FT1 =====
    {
        f32x4 acc[2];
        acc[0] = (f32x4){0.f, 0.f, 0.f, 0.f};
        acc[1] = (f32x4){0.f, 0.f, 0.f, 0.f};
        const int aswz = (arow & 7) << 4;
        for (int kk = 0; kk < 16; ++kk) {
            bf16x4 alo, ahi;
            if (kk < 8) {
                const int ab = arow * 512 + kk * 64 + kg * 8;
                alo = *(const bf16x4*)(hsb + (ab ^ aswz));
                ahi = *(const bf16x4*)(hsb + ((ab + 32) ^ aswz));
            } else {
                const char* gp = (const char*)gembb + (kk - 8) * 64 + kg * 8;
                alo = *(const bf16x4*)(gp);
                ahi = *(const bf16x4*)(gp + 32);
            }
            const bf16x8 afrag = (bf16x8){alo[0], alo[1], alo[2], alo[3],
                                          ahi[0], ahi[1], ahi[2], ahi[3]};
#pragma unroll
            for (int nt = 0; nt < 2; ++nt) {
                const int o = w * 32 + nt * 16 + arow;
                const char* bp = (const char*)FT1 + o * 1024 + kk * 64 + kg * 8;
                const bf16x4 blo = *(const bf16x4*)(bp);
                const bf16x4 bhi = *(const bf16x4*)(bp + 32);
                const bf16x8 bfr = (bf16x8){blo[0], blo[1], blo[2], blo[3],
                                            bhi[0], bhi[1], bhi[2], bhi[3]};
                acc[nt] = __builtin_amdgcn_mfma_f32_16x16x32_bf16(afrag, bfr, acc[nt], 0, 0, 0);
            }
        }
#pragma unroll
        for (int nt = 0; nt < 2; ++nt) {
            const int o = w * 32 + nt * 16 + arow;
            const float wl0 = fc1W[o * 515 + 512];
            const float wl1 = fc1W[o * 515 + 513];
            const float wl2 = fc1W[o * 515 + 514];
            const float b   = fc1b[o];
#pragma unroll
            for (int r = 0; r < 4; ++r) {
                const int row = kg * 4 + r;
                if (row < 8) {
                    float v = acc[nt][r] + b
                            + lash[row][0] * wl0 + lash[row][1] * wl1 + lash[row][2] * wl2;
                    hidn[row][o] = fmaxf(v, 0.f);
                }
            }
        }
    }
    __syncthreads();

    // --- fc2 + output transforms (8 agents x 6 outputs) ---
    if (tid < 48) {
        const int a = tid / 6, j = tid % 6;
        const float* wr = &fc2W[j * 128];
        float acc = fc2b[j];
#pragma unroll
        for (int k = 0; k < 128; ++k) acc += wr[k] * hidn[a][k];
        const int base = (g * 8 + a) * 3;
        if (j < 3) {
            const float lim = (j == 2) ? 3.1415927f : 1.0f;
            out[OUT_MEAN + base + j] = tanhf(acc) * lim;
        } else {
            const float sg = 1.f / (1.f + expf(-acc));
            out[OUT_STD + base + (j - 3)] = 0.01f + sg * (0.3f - 0.01f) + 1e-5f;
        }
    }
}

extern "C" void kernel_launch(void* const* d_in, const int* in_sizes, int n_in,
                              void* d_out, int out_size, void* d_ws, size_t ws_size,
                              hipStream_t stream)
{
    const float* x     = (const float*)d_in[0];
    const float* ea    = (const float*)d_in[2];
    const float* lc_w1 = (const float*)d_in[6];
    const float* lc_b1 = (const float*)d_in[7];
    const float* lc_w2 = (const float*)d_in[8];
    const float* lc_b2 = (const float*)d_in[9];
    const float* lc_wl = (const float*)d_in[10];
    const float* lc_bl = (const float*)d_in[11];
    const float* ld_w1 = (const float*)d_in[12];
    const float* ld_b1 = (const float*)d_in[13];
    const float* ld_w2 = (const float*)d_in[14];
    const float* ld_b2 = (const float*)d_in[15];
    const float* g1_W  = (const float*)d_in[16];
    const float* g1_as = (const float*)d_in[17];
    const float* g1_ad = (const float*)d_in[18];
    const float* g1_We = (const float*)d_in[19];
    const float* g1_ae = (const float*)d_in[20];
    const float* g1_b  = (const float*)d_in[21];
    const float* g2_W  = (const float*)d_in[22];
    const float* g2_as = (const float*)d_in[23];
    const float* g2_ad = (const float*)d_in[24];
    const float* g2_We = (const float*)d_in[25];
    const float* g2_ae = (const float*)d_in[26];
    const float* g2_b  = (const float*)d_in[27];
    const float* g3_W  = (const float*)d_in[28];
    const float* g3_as = (const float*)d_in[29];
    const float* g3_ad = (const float*)d_in[30];
    const float* g3_We = (const float*)d_in[31];
    const float* g3_ae = (const float*)d_in[32];
    const float* g3_b  = (const float*)d_in[33];
    const float* fc1_W = (const float*)d_in[34];
    const float* fc1_b = (const float*)d_in[35];
    const float* fc2_W = (const float*)d_in[36];
    const float* fc2_b = (const float*)d_in[37];

    float* out = (float*)d_out;
    unsigned short* WT2 = (unsigned short*)d_ws;        // 128KB
    unsigned short* WT3 = WT2 + 256 * 256;              // 128KB
    unsigned short* FT1 = WT3 + 256 * 256;              // 128KB
    float* partial = (float*)(FT1 + 128 * 512);         // 1KB

    prep_kernel<<<2944, 256, 0, stream>>>(x, ea, g2_W, g3_W, fc1_W,
                                          lc_w1, lc_b1, lc_w2, lc_b2, lc_wl, lc_bl,
                                          ld_w1, ld_b1, ld_w2, ld_b2,
                                          WT2, WT3, FT1, partial, out);

    graph_kernel<<<NGRAPH, 256, 0, stream>>>(x, ea, partial,
                                             g1_W, g1_as, g1_ad, g1_We, g1_ae, g1_b,
                                             WT2, g2_as, g2_ad, g2_We, g2_ae, g2_b,
                                             WT3, g3_as, g3_ad, g3_We, g3_ae, g3_b,
                                             FT1, fc1_W, fc1_b, fc2_W, fc2_b, out);
}

// Round 10
// 160.749 us; speedup vs baseline: 1.0912x; 1.0912x over previous
//
#include <hip/hip_runtime.h>
#include <math.h>

#define NODES   16384
#define NGRAPH  1024
#define EDGES   245760
#define EPG     240
#define FDIM    256

#define OUT_MEAN  0
#define OUT_STD   24576
#define OUT_SCANS 49152
#define OUT_RECON 376832

typedef __attribute__((ext_vector_type(4))) short bf16x4;
typedef __attribute__((ext_vector_type(8))) short bf16x8;
typedef __attribute__((ext_vector_type(4))) float f32x4;

static __device__ __forceinline__ float lrelu02(float v){ return v > 0.f ? v : 0.2f*v; }

static __device__ __forceinline__ unsigned short f2bf(float f){
    unsigned u = __float_as_uint(f);
    u = (u + 0x7FFFu + ((u >> 16) & 1u)) >> 16;
    return (unsigned short)u;
}
static __device__ __forceinline__ float bf2f(unsigned short h){
    return __uint_as_float(((unsigned)h) << 16);
}

// ============ prep kernel: wtrans + fc1 transpose + ea partials + lidar =====
__global__ __launch_bounds__(256) void prep_kernel(
    const float* __restrict__ x,  const float* __restrict__ ea,
    const float* __restrict__ W2, const float* __restrict__ W3,
    const float* __restrict__ F1,
    const float* __restrict__ w1, const float* __restrict__ b1,
    const float* __restrict__ w2, const float* __restrict__ b2,
    const float* __restrict__ wl, const float* __restrict__ bl,
    const float* __restrict__ dw1, const float* __restrict__ db1,
    const float* __restrict__ dw2, const float* __restrict__ db2,
    unsigned short* __restrict__ T2, unsigned short* __restrict__ T3,
    unsigned short* __restrict__ T1, float* __restrict__ partial,
    float* __restrict__ out)
{
    __shared__ float red[256];
    __shared__ float sc[8][25];
    __shared__ float pooled[8][160];
    __shared__ float hid_lds[8][32];

    const int b = blockIdx.x;
    const int tid = threadIdx.x;

    if (b < 512) {
        const float* W = (b < 256) ? W2 : W3;
        unsigned short* T = (b < 256) ? T2 : T3;
        const int n = b & 255;
        T[n * 256 + tid] = f2bf(W[tid * 256 + n]);
        return;
    }
    if (b < 640) {
        const int o = b - 512;
        const int k0 = tid * 2;
        T1[o * 512 + k0]     = f2bf(F1[o * 515 + k0]);
        T1[o * 512 + k0 + 1] = f2bf(F1[o * 515 + k0 + 1]);
        return;
    }
    if (b < 896) {
        const int base = (b - 640) * 960;
        float s = 0.f;
        for (int i = tid; i < 960; i += 256) s += ea[base + i];
        red[tid] = s; __syncthreads();
        for (int off = 128; off > 0; off >>= 1) {
            if (tid < off) red[tid] += red[tid + off];
            __syncthreads();
        }
        if (tid == 0) partial[b - 640] = red[0];
        return;
    }

    // ---- lidar (verified body) ----
    const int lane = tid & 31;
    const int nl   = tid >> 5;
    const int n    = (b - 896) * 8 + nl;

    if (lane < 20) {
        const float v = x[n * 29 + lane];
        sc[nl][lane + 2] = v;
        out[OUT_SCANS + n * 20 + lane] = v;
    } else if (lane < 25) {
        const int pads[5] = {0, 1, 22, 23, 24};
        sc[nl][pads[lane - 20]] = 0.f;
    }
    __syncthreads();

    {
        const int ic = lane & 15;
        const int hi = lane >> 4;
        float w1r[5];
#pragma unroll
        for (int k = 0; k < 5; ++k) w1r[k] = w1[ic * 5 + k];
        const float b1r = b1[ic];
#pragma unroll
        for (int q = 0; q < 5; ++q) {
            const int u  = 2 * q + hi;
            const int p0 = 2 * u;
            float a = b1r, bb = b1r;
#pragma unroll
            for (int k = 0; k < 5; ++k) {
                a  += sc[nl][p0 + k] * w1r[k];
                bb += sc[nl][p0 + 1 + k] * w1r[k];
            }
            pooled[nl][u * 16 + ic] = fmaxf(fmaxf(a, bb), 0.f);
        }
    }
    __syncthreads();

    float macc = 0.f;
    {
        float wreg[48];
#pragma unroll
        for (int i = 0; i < 12; ++i) {
            const float4 v4 = *(const float4*)&w2[lane * 48 + i * 4];
            wreg[i * 4 + 0] = v4.x; wreg[i * 4 + 1] = v4.y;
            wreg[i * 4 + 2] = v4.z; wreg[i * 4 + 3] = v4.w;
        }
        const float b2r = b2[lane];
        float pc[3][16];
#pragma unroll
        for (int i = 0; i < 4; ++i) {
            const float4 v0 = *(const float4*)&pooled[nl][0 * 16 + i * 4];
            const float4 v1 = *(const float4*)&pooled[nl][1 * 16 + i * 4];
            pc[0][i * 4 + 0] = v0.x; pc[0][i * 4 + 1] = v0.y; pc[0][i * 4 + 2] = v0.z; pc[0][i * 4 + 3] = v0.w;
            pc[1][i * 4 + 0] = v1.x; pc[1][i * 4 + 1] = v1.y; pc[1][i * 4 + 2] = v1.z; pc[1][i * 4 + 3] = v1.w;
            pc[2][i * 4 + 0] = 0.f;  pc[2][i * 4 + 1] = 0.f;  pc[2][i * 4 + 2] = 0.f;  pc[2][i * 4 + 3] = 0.f;
        }
#pragma unroll
        for (int t = 0; t < 10; ++t) {
            const int prev = (t + 2) % 3, cur = t % 3, nxt = (t + 1) % 3;
            if (t >= 1) {
                if (t + 1 <= 9) {
#pragma unroll
                    for (int i = 0; i < 4; ++i) {
                        const float4 v4 = *(const float4*)&pooled[nl][(t + 1) * 16 + i * 4];
                        pc[nxt][i * 4 + 0] = v4.x; pc[nxt][i * 4 + 1] = v4.y;
                        pc[nxt][i * 4 + 2] = v4.z; pc[nxt][i * 4 + 3] = v4.w;
                    }
                } else {
#pragma unroll
                    for (int ic = 0; ic < 16; ++ic) pc[nxt][ic] = 0.f;
                }
            }
            float v = b2r;
#pragma unroll
            for (int ic = 0; ic < 16; ++ic) {
                v += pc[prev][ic] * wreg[ic * 3 + 0]
                   + pc[cur][ic]  * wreg[ic * 3 + 1]
                   + pc[nxt][ic]  * wreg[ic * 3 + 2];
            }
            macc += fmaxf(v, 0.f);
        }
    }

    const float feat = macc * 0.1f;
    float z[5];
#pragma unroll
    for (int j = 0; j < 5; ++j) {
        float p = feat * wl[j * 32 + lane];
        p += __shfl_xor(p, 1);
        p += __shfl_xor(p, 2);
        p += __shfl_xor(p, 4);
        p += __shfl_xor(p, 8);
        p += __shfl_xor(p, 16);
        z[j] = fmaxf(bl[j] + p, 0.f);
    }
    float hv = db1[lane];
#pragma unroll
    for (int j = 0; j < 5; ++j) hv += z[j] * dw1[lane * 5 + j];
    hid_lds[nl][lane] = fmaxf(hv, 0.f);
    __syncthreads();

    if (lane < 20) {
        float acc = db2[lane];
#pragma unroll
        for (int k = 0; k < 32; ++k) acc += hid_lds[nl][k] * dw2[lane * 32 + k];
        out[OUT_RECON + n * 20 + lane] = acc;
    }
}

// ============ per-graph WAVE kernel: one 64-lane wave = one graph ===========
// 1024 blocks x 64 threads; all barriers are intra-wave (near-free).
// LDS ~36KB -> 4 blocks/CU -> all 1024 waves resident (one per SIMD).
__global__ __launch_bounds__(64) void graph_kernel(
    const float* __restrict__ x,   const float* __restrict__ ea,
    const float* __restrict__ partial,
    const float* __restrict__ g1_W,
    const float* __restrict__ g1_as, const float* __restrict__ g1_ad,
    const float* __restrict__ g1_We, const float* __restrict__ g1_ae,
    const float* __restrict__ g1_b,
    const unsigned short* __restrict__ WT2,
    const float* __restrict__ g2_as, const float* __restrict__ g2_ad,
    const float* __restrict__ g2_We, const float* __restrict__ g2_ae,
    const float* __restrict__ g2_b,
    const unsigned short* __restrict__ WT3,
    const float* __restrict__ g3_as, const float* __restrict__ g3_ad,
    const float* __restrict__ g3_We, const float* __restrict__ g3_ae,
    const float* __restrict__ g3_b,
    const unsigned short* __restrict__ FT1,
    const float* __restrict__ fc1W, const float* __restrict__ fc1b,
    const float* __restrict__ fc2W, const float* __restrict__ fc2b,
    float* __restrict__ out)
{
    __shared__ char  hsb[8192] __attribute__((aligned(16)));   // bf16 h tile, swizzled
    __shared__ float xwf[16 * 264];                            // xw fp32, [i][h][c] pad33
    __shared__ unsigned short coefb[8][16][20] __attribute__((aligned(8)));
    __shared__ float sals[16][8], sald[16][8];
    __shared__ float sasrc[256], sadst[256], sS[8];
    __shared__ float hs6[16][6];
    __shared__ float lash[8][3];
    __shared__ float hidn[8 * 132];                            // pad 132 vs 128
    __shared__ unsigned short gembb[256];

    const int lane = threadIdx.x, g = blockIdx.x;
    const int arow = lane & 15, kg = lane >> 4;

    // --- edge-attr mean (register butterfly, all lanes end with the value) ---
    float eamean;
    {
        float pv = partial[lane] + partial[lane + 64] + partial[lane + 128] + partial[lane + 192];
        pv += __shfl_xor(pv, 1);
        pv += __shfl_xor(pv, 2);
        pv += __shfl_xor(pv, 4);
        pv += __shfl_xor(pv, 8);
        pv += __shfl_xor(pv, 16);
        pv += __shfl_xor(pv, 32);
        eamean = pv * (1.f / (float)EDGES);
    }

    // --- stage L1 inputs ---
    for (int t = lane; t < 96; t += 64) hs6[t / 6][t % 6] = x[(g * 16 + t / 6) * 29 + 20 + t % 6];
    if (lane < 24) lash[lane / 3][lane % 3] = x[(g * 16 + lane / 3) * 29 + 26 + lane % 3];
    *(float4*)&sasrc[lane * 4] = *(const float4*)&g1_as[lane * 4];
    *(float4*)&sadst[lane * 4] = *(const float4*)&g1_ad[lane * 4];
    {
        const int h = lane >> 3, c0 = (lane & 7) * 4;
        float s = 0.f;
#pragma unroll
        for (int c = 0; c < 4; ++c) s += g1_We[h * 32 + c0 + c] * g1_ae[h * 32 + c0 + c];
        s += __shfl_xor(s, 1); s += __shfl_xor(s, 2); s += __shfl_xor(s, 4);
        if ((lane & 7) == 0) sS[h] = s;
    }
    __syncthreads();

    // ===== L1 GEMM K=6 (VALU): lane owns cols lane*4 .. lane*4+3 =====
    float acc1[16][4];
    {
#pragma unroll
        for (int i = 0; i < 16; ++i)
#pragma unroll
            for (int cc = 0; cc < 4; ++cc) acc1[i][cc] = 0.f;
#pragma unroll
        for (int k = 0; k < 6; ++k) {
            const float4 wv = *(const float4*)&g1_W[k * 256 + lane * 4];
#pragma unroll
            for (int i = 0; i < 16; ++i) {
                const float hv = hs6[i][k];
                acc1[i][0] += hv * wv.x; acc1[i][1] += hv * wv.y;
                acc1[i][2] += hv * wv.z; acc1[i][3] += hv * wv.w;
            }
        }
        const int hcol = lane >> 3, cin = (lane & 7) * 4;
#pragma unroll
        for (int i = 0; i < 16; ++i)
#pragma unroll
            for (int cc = 0; cc < 4; ++cc) xwf[i * 264 + hcol * 33 + cin + cc] = acc1[i][cc];
    }
    __syncthreads();

    // --- L1 dots: 256 tasks (i,h,sd), 4 per lane; conflict-free via pad33 ---
#pragma unroll
    for (int rep = 0; rep < 4; ++rep) {
        const int task = rep * 64 + lane;
        const int i = task >> 4, h = (task >> 1) & 7;
        const float* av = (task & 1) ? &sadst[h * 32] : &sasrc[h * 32];
        const float* xr = &xwf[i * 264 + h * 33];
        float s = 0.f;
#pragma unroll
        for (int c = 0; c < 32; ++c) s += xr[c] * av[c];
        if (task & 1) sald[i][h] = s; else sals[i][h] = s;
    }
    __syncthreads();

    // --- L1 softmax (no self loop): 128 rows, 2 per lane -> coefb[h][d][s] ---
#pragma unroll
    for (int rep = 0; rep < 2; ++rep) {
        const int row = rep * 64 + lane;
        const int d = row >> 3, h = row & 7;
        const float S = sS[h];
        const float aldv = sald[d][h];
        float alf[16];
        float m = -1e30f;
#pragma unroll
        for (int s = 0; s < 16; ++s) {
            float a;
            if (s == d) a = -1e30f;
            else {
                const int el = s * 15 + d - (d > s ? 1 : 0);
                a = lrelu02(sals[s][h] + aldv + ea[g * EPG + el] * S);
            }
            alf[s] = a;
            m = fmaxf(m, a);
        }
        float sum = 0.f;
#pragma unroll
        for (int s = 0; s < 16; ++s) { alf[s] = expf(alf[s] - m); sum += alf[s]; }
        const float r = 1.f / (sum + 1e-16f);
#pragma unroll
        for (int s = 0; s < 16; ++s) coefb[h][d][s] = f2bf(alf[s] * r);
    }
    __syncthreads();

    // --- L1 aggregate (VALU, acc1 regs are xw[s][col]) -> hsb bf16 swizzled ---
    {
        const int hcol = lane >> 3;
#pragma unroll
        for (int cc = 0; cc < 4; ++cc) {
            const int col = lane * 4 + cc;
            const float b = g1_b[col];
            float od[16];
#pragma unroll
            for (int d = 0; d < 16; ++d) {
                float v = b;
#pragma unroll
                for (int s4 = 0; s4 < 4; ++s4) {
                    const bf16x4 cv = *(const bf16x4*)((const char*)coefb + hcol * 640 + d * 40 + s4 * 8);
                    v += bf2f((unsigned short)cv[0]) * acc1[s4 * 4 + 0][cc]
                       + bf2f((unsigned short)cv[1]) * acc1[s4 * 4 + 1][cc]
                       + bf2f((unsigned short)cv[2]) * acc1[s4 * 4 + 2][cc]
                       + bf2f((unsigned short)cv[3]) * acc1[s4 * 4 + 3][cc];
                }
                od[d] = v;
            }
#pragma unroll
            for (int d = 0; d < 16; ++d)
                *(unsigned short*)(hsb + ((d * 512 + col * 2) ^ ((d & 7) << 4))) = f2bf(fmaxf(od[d], 0.f));
        }
    }
    __syncthreads();

    // ===== layers 2 and 3 =====
#pragma unroll 1
    for (int ly = 0; ly < 2; ++ly) {
        const unsigned short* WT = ly ? WT3 : WT2;
        const float* as_ = ly ? g3_as : g2_as;
        const float* ad_ = ly ? g3_ad : g2_ad;
        const float* We_ = ly ? g3_We : g2_We;
        const float* ae_ = ly ? g3_ae : g2_ae;
        const float* bi_ = ly ? g3_b  : g2_b;

        *(float4*)&sasrc[lane * 4] = *(const float4*)&as_[lane * 4];
        *(float4*)&sadst[lane * 4] = *(const float4*)&ad_[lane * 4];
        {
            const int h = lane >> 3, c0 = (lane & 7) * 4;
            float s = 0.f;
#pragma unroll
            for (int c = 0; c < 4; ++c) s += We_[h * 32 + c0 + c] * ae_[h * 32 + c0 + c];
            s += __shfl_xor(s, 1); s += __shfl_xor(s, 2); s += __shfl_xor(s, 4);
            if ((lane & 7) == 0) sS[h] = s;
        }

        // --- MFMA GEMM: whole 16x256 tile in one wave (16 nt), bfrag kept ---
        bf16x4 bfrag[16];
        {
            f32x4 acc[16];
#pragma unroll
            for (int nt = 0; nt < 16; ++nt) acc[nt] = (f32x4){0.f, 0.f, 0.f, 0.f};
            const int aswz = (arow & 7) << 4;
            const char* wt = (const char*)WT;
            for (int kk = 0; kk < 8; ++kk) {
                const int ab = arow * 512 + kk * 64 + kg * 8;
                const bf16x4 alo = *(const bf16x4*)(hsb + (ab ^ aswz));
                const bf16x4 ahi = *(const bf16x4*)(hsb + ((ab + 32) ^ aswz));
                const bf16x8 afrag = (bf16x8){alo[0], alo[1], alo[2], alo[3],
                                              ahi[0], ahi[1], ahi[2], ahi[3]};
#pragma unroll
                for (int nt = 0; nt < 16; ++nt) {
                    const int ncol = nt * 16 + arow;
                    const char* bp = wt + ncol * 512 + kk * 64 + kg * 8;
                    const bf16x4 blo = *(const bf16x4*)(bp);
                    const bf16x4 bhi = *(const bf16x4*)(bp + 32);
                    const bf16x8 bfr = (bf16x8){blo[0], blo[1], blo[2], blo[3],
                                                bhi[0], bhi[1], bhi[2], bhi[3]};
                    acc[nt] = __builtin_amdgcn_mfma_f32_16x16x32_bf16(afrag, bfr, acc[nt], 0, 0, 0);
                }
            }
            // D rows kg*4+r at col nt*16+arow -> xwf (fp32) + bfrag (bf16)
#pragma unroll
            for (int nt = 0; nt < 16; ++nt) {
                const int col = nt * 16 + arow;
                const int hc = col >> 5, ci = col & 31;
#pragma unroll
                for (int r = 0; r < 4; ++r) xwf[(kg * 4 + r) * 264 + hc * 33 + ci] = acc[nt][r];
                bfrag[nt] = (bf16x4){(short)f2bf(acc[nt][0]), (short)f2bf(acc[nt][1]),
                                     (short)f2bf(acc[nt][2]), (short)f2bf(acc[nt][3])};
            }
        }
        __syncthreads();

        // --- dots ---
#pragma unroll
        for (int rep = 0; rep < 4; ++rep) {
            const int task = rep * 64 + lane;
            const int i = task >> 4, h = (task >> 1) & 7;
            const float* av = (task & 1) ? &sadst[h * 32] : &sasrc[h * 32];
            const float* xr = &xwf[i * 264 + h * 33];
            float s = 0.f;
#pragma unroll
            for (int c = 0; c < 32; ++c) s += xr[c] * av[c];
            if (task & 1) sald[i][h] = s; else sals[i][h] = s;
        }
        __syncthreads();

        // --- softmax (self loop with eamean) ---
#pragma unroll
        for (int rep = 0; rep < 2; ++rep) {
            const int row = rep * 64 + lane;
            const int d = row >> 3, h = row & 7;
            const float S = sS[h];
            const float aldv = sald[d][h];
            float alf[16];
            float m = -1e30f;
#pragma unroll
            for (int s = 0; s < 16; ++s) {
                float a;
                if (s == d) a = lrelu02(sals[s][h] + aldv + eamean * S);
                else {
                    const int el = s * 15 + d - (d > s ? 1 : 0);
                    a = lrelu02(sals[s][h] + aldv + ea[g * EPG + el] * S);
                }
                alf[s] = a;
                m = fmaxf(m, a);
            }
            float sum = 0.f;
#pragma unroll
            for (int s = 0; s < 16; ++s) { alf[s] = expf(alf[s] - m); sum += alf[s]; }
            const float r = 1.f / (sum + 1e-16f);
#pragma unroll
            for (int s = 0; s < 16; ++s) coefb[h][d][s] = f2bf(alf[s] * r);
        }
        __syncthreads();

        // --- aggregate via MFMA (R9-verified mapping), B from bfrag regs ---
        {
#pragma unroll
            for (int nt = 0; nt < 16; ++nt) {
                const int h = nt >> 1;
                const bf16x4 alo = *(const bf16x4*)((const char*)coefb + h * 640 + arow * 40 + kg * 8);
                const bf16x8 afrag = (bf16x8){alo[0], alo[1], alo[2], alo[3], 0, 0, 0, 0};
                const bf16x8 bfr   = (bf16x8){bfrag[nt][0], bfrag[nt][1], bfrag[nt][2], bfrag[nt][3],
                                              0, 0, 0, 0};
                f32x4 hacc = __builtin_amdgcn_mfma_f32_16x16x32_bf16(
                                 afrag, bfr, (f32x4){0.f, 0.f, 0.f, 0.f}, 0, 0, 0);
                const int c2 = nt * 16 + arow;
                const float b = bi_[c2];
                float p = 0.f;
#pragma unroll
                for (int r = 0; r < 4; ++r) {
                    const float hv = fmaxf(hacc[r] + b, 0.f);
                    p += hv;
                    const int d = kg * 4 + r;
                    *(unsigned short*)(hsb + ((d * 512 + c2 * 2) ^ ((d & 7) << 4))) = f2bf(hv);
                }
                if (ly == 1) {
                    p += __shfl_xor(p, 16);
                    p += __shfl_xor(p, 32);
                    if (kg == 0) gembb[c2] = f2bf(p * (1.f / 16.f));
                }
            }
        }
        __syncthreads();
    }

    // ===== heads fc1 via MFMA: A = [hsb | gembb-broadcast], 8 nt in wave =====
    {
        f32x4 acc2[8];
#pragma unroll
        for (int nt = 0; nt < 8; ++nt) acc2[nt] = (f32x4){0.f, 0.f, 0.f, 0.f};
        const int aswz = (arow & 7) << 4;
        for (int kk = 0; kk < 16; ++kk) {
            bf16x4 alo, ahi;
            if (kk < 8) {
                const int ab = arow * 512 + kk * 64 + kg * 8;
                alo = *(const bf16x4*)(hsb + (ab ^ aswz));
                ahi = *(const bf16x4*)(hsb + ((ab + 32) ^ aswz));
            } else {
                const char* gp = (const char*)gembb + (kk - 8) * 64 + kg * 8;
                alo = *(const bf16x4*)(gp);
                ahi = *(const bf16x4*)(gp + 32);
            }
            const bf16x8 afrag = (bf16x8){alo[0], alo[1], alo[2], alo[3],
                                          ahi[0], ahi[1], ahi[2], ahi[3]};
#pragma unroll
            for (int nt = 0; nt < 8; ++nt) {
                const int o = nt * 16 + arow;
                const char* bp = (const char*)FT1 + o * 1024 + kk * 64 + kg * 8;
                const bf16x4 blo = *(const bf16x4*)(bp);
                const bf16x4 bhi = *(const bf16x4*)(bp + 32);
                const bf16x8 bfr = (bf16x8){blo[0], blo[1], blo[2], blo[3],
                                            bhi[0], bhi[1], bhi[2], bhi[3]};
                acc2[nt] = __builtin_amdgcn_mfma_f32_16x16x32_bf16(afrag, bfr, acc2[nt], 0, 0, 0);
            }
        }
#pragma unroll
        for (int nt = 0; nt < 8; ++nt) {
            const int o = nt * 16 + arow;
            const float wl0 = fc1W[o * 515 + 512];
            const float wl1 = fc1W[o * 515 + 513];
            const float wl2 = fc1W[o * 515 + 514];
            const float b   = fc1b[o];
#pragma unroll
            for (int r = 0; r < 4; ++r) {
                const int row = kg * 4 + r;
                if (row < 8) {
                    float v = acc2[nt][r] + b
                            + lash[row][0] * wl0 + lash[row][1] * wl1 + lash[row][2] * wl2;
                    hidn[row * 132 + o] = fmaxf(v, 0.f);
                }
            }
        }
    }
    __syncthreads();

    // --- fc2 + output transforms (8 agents x 6 outputs) ---
    if (lane < 48) {
        const int a = lane / 6, j = lane % 6;
        const float* wr = &fc2W[j * 128];
        float acc = fc2b[j];
#pragma unroll
        for (int k = 0; k < 128; ++k) acc += wr[k] * hidn[a * 132 + k];
        const int base = (g * 8 + a) * 3;
        if (j < 3) {
            const float lim = (j == 2) ? 3.1415927f : 1.0f;
            out[OUT_MEAN + base + j] = tanhf(acc) * lim;
        } else {
            const float sg = 1.f / (1.f + expf(-acc));
            out[OUT_STD + base + (j - 3)] = 0.01f + sg * (0.3f - 0.01f) + 1e-5f;
        }
    }
}

extern "C" void kernel_launch(void* const* d_in, const int* in_sizes, int n_in,
                              void* d_out, int out_size, void* d_ws, size_t ws_size,
                              hipStream_t stream)
{
    const float* x     = (const float*)d_in[0];
    const float* ea    = (const float*)d_in[2];
    const float* lc_w1 = (const float*)d_in[6];
    const float* lc_b1 = (const float*)d_in[7];
    const float* lc_w2 = (const float*)d_in[8];
    const float* lc_b2 = (const float*)d_in[9];
    const float* lc_wl = (const float*)d_in[10];
    const float* lc_bl = (const float*)d_in[11];
    const float* ld_w1 = (const float*)d_in[12];
    const float* ld_b1 = (const float*)d_in[13];
    const float* ld_w2 = (const float*)d_in[14];
    const float* ld_b2 = (const float*)d_in[15];
    const float* g1_W  = (const float*)d_in[16];
    const float* g1_as = (const float*)d_in[17];
    const float* g1_ad = (const float*)d_in[18];
    const float* g1_We = (const float*)d_in[19];
    const float* g1_ae = (const float*)d_in[20];
    const float* g1_b  = (const float*)d_in[21];
    const float* g2_W  = (const float*)d_in[22];
    const float* g2_as = (const float*)d_in[23];
    const float* g2_ad = (const float*)d_in[24];
    const float* g2_We = (const float*)d_in[25];
    const float* g2_ae = (const float*)d_in[26];
    const float* g2_b  = (const float*)d_in[27];
    const float* g3_W  = (const float*)d_in[28];
    const float* g3_as = (const float*)d_in[29];
    const float* g3_ad = (const float*)d_in[30];
    const float* g3_We = (const float*)d_in[31];
    const float* g3_ae = (const float*)d_in[32];
    const float* g3_b  = (const float*)d_in[33];
    const float* fc1_W = (const float*)d_in[34];
    const float* fc1_b = (const float*)d_in[35];
    const float* fc2_W = (const float*)d_in[36];
    const float* fc2_b = (const float*)d_in[37];

    float* out = (float*)d_out;
    unsigned short* WT2 = (unsigned short*)d_ws;        // 128KB
    unsigned short* WT3 = WT2 + 256 * 256;              // 128KB
    unsigned short* FT1 = WT3 + 256 * 256;              // 128KB
    float* partial = (float*)(FT1 + 128 * 512);         // 1KB

    prep_kernel<<<2944, 256, 0, stream>>>(x, ea, g2_W, g3_W, fc1_W,
                                          lc_w1, lc_b1, lc_w2, lc_b2, lc_wl, lc_bl,
                                          ld_w1, ld_b1, ld_w2, ld_b2,
                                          WT2, WT3, FT1, partial, out);

    graph_kernel<<<NGRAPH, 64, 0, stream>>>(x, ea, partial,
                                            g1_W, g1_as, g1_ad, g1_We, g1_ae, g1_b,
                                            WT2, g2_as, g2_ad, g2_We, g2_ae, g2_b,
                                            WT3, g3_as, g3_ad, g3_We, g3_ae, g3_b,
                                            FT1, fc1_W, fc1_b, fc2_W, fc2_b, out);
}

// Round 12
// 160.397 us; speedup vs baseline: 1.0936x; 1.0022x over previous
//
#include <hip/hip_runtime.h>
#include <math.h>

#define NODES   16384
#define NGRAPH  1024
#define EDGES   245760
#define EPG     240
#define FDIM    256

#define OUT_MEAN  0
#define OUT_STD   24576
#define OUT_SCANS 49152
#define OUT_RECON 376832

typedef __attribute__((ext_vector_type(4))) short bf16x4;
typedef __attribute__((ext_vector_type(8))) short bf16x8;
typedef __attribute__((ext_vector_type(4))) float f32x4;

static __device__ __forceinline__ float lrelu02(float v){ return v > 0.f ? v : 0.2f*v; }

static __device__ __forceinline__ unsigned short f2bf(float f){
    unsigned u = __float_as_uint(f);
    u = (u + 0x7FFFu + ((u >> 16) & 1u)) >> 16;
    return (unsigned short)u;
}
static __device__ __forceinline__ float bf2f(unsigned short h){
    return __uint_as_float(((unsigned)h) << 16);
}

// ===== prep: WTE2/WTE3 (272x256, W^T + folded a_src/a_dst cols), W1E, FT1,
//       ea partials, lidar =====
// blocks: [0,272) WTE2 | [272,544) WTE3 | 544 W1E | [545,673) FT1 |
//         [673,929) ea | [929,2977) lidar
__global__ __launch_bounds__(256) void prep_kernel(
    const float* __restrict__ x,  const float* __restrict__ ea,
    const float* __restrict__ W2, const float* __restrict__ as2, const float* __restrict__ ad2,
    const float* __restrict__ W3, const float* __restrict__ as3, const float* __restrict__ ad3,
    const float* __restrict__ W1, const float* __restrict__ as1, const float* __restrict__ ad1,
    const float* __restrict__ F1,
    const float* __restrict__ w1, const float* __restrict__ b1,
    const float* __restrict__ w2, const float* __restrict__ b2,
    const float* __restrict__ wl, const float* __restrict__ bl,
    const float* __restrict__ dw1, const float* __restrict__ db1,
    const float* __restrict__ dw2, const float* __restrict__ db2,
    unsigned short* __restrict__ T2, unsigned short* __restrict__ T3,
    float* __restrict__ W1E, unsigned short* __restrict__ T1,
    float* __restrict__ partial, float* __restrict__ out)
{
    __shared__ float red[256];
    __shared__ float sc[8][25];
    __shared__ float pooled[8][160];
    __shared__ float hid_lds[8][32];

    const int b = blockIdx.x;
    const int tid = threadIdx.x;

    if (b < 544) {
        const float* W   = (b < 272) ? W2 : W3;
        const float* as_ = (b < 272) ? as2 : as3;
        const float* ad_ = (b < 272) ? ad2 : ad3;
        unsigned short* T = (b < 272) ? T2 : T3;
        const int n = (b < 272) ? b : b - 272;
        if (n < 256) {
            T[n * 256 + tid] = f2bf(W[tid * 256 + n]);
        } else {
            const int j = n - 256, h = j & 7;
            const float* av = (j < 8) ? as_ : ad_;
            float s = 0.f;
            for (int c = 0; c < 32; ++c) s += W[tid * 256 + h * 32 + c] * av[h * 32 + c];
            T[n * 256 + tid] = f2bf(s);
        }
        return;
    }
    if (b == 544) {
        for (int c = tid; c < 272; c += 256) {
            for (int k = 0; k < 6; ++k) {
                float v;
                if (c < 256) v = W1[k * 256 + c];
                else {
                    const int j = c - 256, h = j & 7;
                    const float* av = (j < 8) ? as1 : ad1;
                    float s = 0.f;
                    for (int cc = 0; cc < 32; ++cc) s += W1[k * 256 + h * 32 + cc] * av[h * 32 + cc];
                    v = s;
                }
                W1E[k * 272 + c] = v;
            }
        }
        return;
    }
    if (b < 673) {
        const int o = b - 545;
        const int k0 = tid * 2;
        T1[o * 512 + k0]     = f2bf(F1[o * 515 + k0]);
        T1[o * 512 + k0 + 1] = f2bf(F1[o * 515 + k0 + 1]);
        return;
    }
    if (b < 929) {
        const int base = (b - 673) * 960;
        float s = 0.f;
        for (int i = tid; i < 960; i += 256) s += ea[base + i];
        red[tid] = s; __syncthreads();
        for (int off = 128; off > 0; off >>= 1) {
            if (tid < off) red[tid] += red[tid + off];
            __syncthreads();
        }
        if (tid == 0) partial[b - 673] = red[0];
        return;
    }

    // ---- lidar (verified body) ----
    const int lane = tid & 31;
    const int nl   = tid >> 5;
    const int n    = (b - 929) * 8 + nl;

    if (lane < 20) {
        const float v = x[n * 29 + lane];
        sc[nl][lane + 2] = v;
        out[OUT_SCANS + n * 20 + lane] = v;
    } else if (lane < 25) {
        const int pads[5] = {0, 1, 22, 23, 24};
        sc[nl][pads[lane - 20]] = 0.f;
    }
    __syncthreads();

    {
        const int ic = lane & 15;
        const int hi = lane >> 4;
        float w1r[5];
#pragma unroll
        for (int k = 0; k < 5; ++k) w1r[k] = w1[ic * 5 + k];
        const float b1r = b1[ic];
#pragma unroll
        for (int q = 0; q < 5; ++q) {
            const int u  = 2 * q + hi;
            const int p0 = 2 * u;
            float a = b1r, bb = b1r;
#pragma unroll
            for (int k = 0; k < 5; ++k) {
                a  += sc[nl][p0 + k] * w1r[k];
                bb += sc[nl][p0 + 1 + k] * w1r[k];
            }
            pooled[nl][u * 16 + ic] = fmaxf(fmaxf(a, bb), 0.f);
        }
    }
    __syncthreads();

    float macc = 0.f;
    {
        float wreg[48];
#pragma unroll
        for (int i = 0; i < 12; ++i) {
            const float4 v4 = *(const float4*)&w2[lane * 48 + i * 4];
            wreg[i * 4 + 0] = v4.x; wreg[i * 4 + 1] = v4.y;
            wreg[i * 4 + 2] = v4.z; wreg[i * 4 + 3] = v4.w;
        }
        const float b2r = b2[lane];
        float pc[3][16];
#pragma unroll
        for (int i = 0; i < 4; ++i) {
            const float4 v0 = *(const float4*)&pooled[nl][0 * 16 + i * 4];
            const float4 v1 = *(const float4*)&pooled[nl][1 * 16 + i * 4];
            pc[0][i * 4 + 0] = v0.x; pc[0][i * 4 + 1] = v0.y; pc[0][i * 4 + 2] = v0.z; pc[0][i * 4 + 3] = v0.w;
            pc[1][i * 4 + 0] = v1.x; pc[1][i * 4 + 1] = v1.y; pc[1][i * 4 + 2] = v1.z; pc[1][i * 4 + 3] = v1.w;
            pc[2][i * 4 + 0] = 0.f;  pc[2][i * 4 + 1] = 0.f;  pc[2][i * 4 + 2] = 0.f;  pc[2][i * 4 + 3] = 0.f;
        }
#pragma unroll
        for (int t = 0; t < 10; ++t) {
            const int prev = (t + 2) % 3, cur = t % 3, nxt = (t + 1) % 3;
            if (t >= 1) {
                if (t + 1 <= 9) {
#pragma unroll
                    for (int i = 0; i < 4; ++i) {
                        const float4 v4 = *(const float4*)&pooled[nl][(t + 1) * 16 + i * 4];
                        pc[nxt][i * 4 + 0] = v4.x; pc[nxt][i * 4 + 1] = v4.y;
                        pc[nxt][i * 4 + 2] = v4.z; pc[nxt][i * 4 + 3] = v4.w;
                    }
                } else {
#pragma unroll
                    for (int ic = 0; ic < 16; ++ic) pc[nxt][ic] = 0.f;
                }
            }
            float v = b2r;
#pragma unroll
            for (int ic = 0; ic < 16; ++ic) {
                v += pc[prev][ic] * wreg[ic * 3 + 0]
                   + pc[cur][ic]  * wreg[ic * 3 + 1]
                   + pc[nxt][ic]  * wreg[ic * 3 + 2];
            }
            macc += fmaxf(v, 0.f);
        }
    }

    const float feat = macc * 0.1f;
    float z[5];
#pragma unroll
    for (int j = 0; j < 5; ++j) {
        float p = feat * wl[j * 32 + lane];
        p += __shfl_xor(p, 1);
        p += __shfl_xor(p, 2);
        p += __shfl_xor(p, 4);
        p += __shfl_xor(p, 8);
        p += __shfl_xor(p, 16);
        z[j] = fmaxf(bl[j] + p, 0.f);
    }
    float hv = db1[lane];
#pragma unroll
    for (int j = 0; j < 5; ++j) hv += z[j] * dw1[lane * 5 + j];
    hid_lds[nl][lane] = fmaxf(hv, 0.f);
    __syncthreads();

    if (lane < 20) {
        float acc = db2[lane];
#pragma unroll
        for (int k = 0; k < 32; ++k) acc += hid_lds[nl][k] * dw2[lane * 32 + k];
        out[OUT_RECON + n * 20 + lane] = acc;
    }
}

// ===== per-graph kernel: 128 threads (2 waves), K-split GEMM, folded als/ald
__global__ __launch_bounds__(128) void graph_kernel(
    const float* __restrict__ x,   const float* __restrict__ ea,
    const float* __restrict__ partial,
    const float* __restrict__ W1E,
    const float* __restrict__ g1_We, const float* __restrict__ g1_ae,
    const float* __restrict__ g1_b,
    const unsigned short* __restrict__ WTE2,
    const float* __restrict__ g2_We, const float* __restrict__ g2_ae,
    const float* __restrict__ g2_b,
    const unsigned short* __restrict__ WTE3,
    const float* __restrict__ g3_We, const float* __restrict__ g3_ae,
    const float* __restrict__ g3_b,
    const unsigned short* __restrict__ FT1,
    const float* __restrict__ fc1W, const float* __restrict__ fc1b,
    const float* __restrict__ fc2W, const float* __restrict__ fc2b,
    float* __restrict__ out)
{
    __shared__ char  hsb[8192] __attribute__((aligned(16)));   // bf16 h, swizzled
    __shared__ float xwp[16][282];                             // fp32 xw + als/ald cols
    __shared__ unsigned short coefb[8][16][20] __attribute__((aligned(8)));
    __shared__ float sS[8];
    __shared__ float hs6[16][6];
    __shared__ float lash[8][3];
    __shared__ float hidn[8][132];
    __shared__ unsigned short gembb[256] __attribute__((aligned(8)));

    const int tid = threadIdx.x, g = blockIdx.x;
    const int lane = tid & 63, w = tid >> 6;
    const int arow = lane & 15, kg = lane >> 4;

    // --- edge-attr mean (per-wave butterfly, deterministic) ---
    float eamean;
    {
        float pv = partial[lane] + partial[lane + 64] + partial[lane + 128] + partial[lane + 192];
        pv += __shfl_xor(pv, 1);
        pv += __shfl_xor(pv, 2);
        pv += __shfl_xor(pv, 4);
        pv += __shfl_xor(pv, 8);
        pv += __shfl_xor(pv, 16);
        pv += __shfl_xor(pv, 32);
        eamean = pv * (1.f / (float)EDGES);
    }

    // --- stage inputs ---
    if (tid < 96) hs6[tid / 6][tid % 6] = x[(g * 16 + tid / 6) * 29 + 20 + tid % 6];
    if (tid >= 96 && tid < 120) {
        const int t = tid - 96;
        lash[t / 3][t % 3] = x[(g * 16 + t / 3) * 29 + 26 + t % 3];
    }
    if (tid < 8) {
        float s = 0.f;
        for (int c = 0; c < 32; ++c) s += g1_We[tid * 32 + c] * g1_ae[tid * 32 + c];
        sS[tid] = s;
    }
    __syncthreads();

    // ===== L1 GEMM (K=6, VALU, 272 cols incl. folded als/ald) -> xwp =====
    // FIX (R11 bug): grid-stride over all 272 cols with 128 threads; the old
    // `tid < 136` mapping left cols 256..271 (folded als/ald) unwritten.
    for (int c = tid; c < 272; c += 128) {
        float col[16];
#pragma unroll
        for (int i = 0; i < 16; ++i) col[i] = 0.f;
#pragma unroll
        for (int k = 0; k < 6; ++k) {
            const float wv = W1E[k * 272 + c];
#pragma unroll
            for (int i = 0; i < 16; ++i) col[i] += hs6[i][k] * wv;
        }
#pragma unroll
        for (int i = 0; i < 16; ++i) xwp[i][c] = col[i];
    }
    __syncthreads();

    // ===== L1 softmax (no self loop), 128 rows -> coefb =====
    {
        const int d = tid >> 3, h = tid & 7;
        const float S = sS[h];
        const float aldv = xwp[d][264 + h];
        float alf[16];
        float m = -1e30f;
#pragma unroll
        for (int s = 0; s < 16; ++s) {
            float a;
            if (s == d) a = -1e30f;
            else {
                const int el = s * 15 + d - (d > s ? 1 : 0);
                a = lrelu02(xwp[s][256 + h] + aldv + ea[g * EPG + el] * S);
            }
            alf[s] = a;
            m = fmaxf(m, a);
        }
        float sum = 0.f;
#pragma unroll
        for (int s = 0; s < 16; ++s) { alf[s] = expf(alf[s] - m); sum += alf[s]; }
        const float r = 1.f / (sum + 1e-16f);
#pragma unroll
        for (int s = 0; s < 16; ++s) coefb[h][d][s] = f2bf(alf[s] * r);
    }
    __syncthreads();

    // ===== L1 aggregate (VALU) -> hsb =====
#pragma unroll
    for (int cc = 0; cc < 2; ++cc) {
        const int c = tid + cc * 128;
        const int h = c >> 5;
        const float b = g1_b[c];
        float xc[16];
#pragma unroll
        for (int s = 0; s < 16; ++s) xc[s] = xwp[s][c];
#pragma unroll
        for (int d = 0; d < 16; ++d) {
            float v = b;
#pragma unroll
            for (int s4 = 0; s4 < 4; ++s4) {
                const bf16x4 cv = *(const bf16x4*)((const char*)coefb + h * 640 + d * 40 + s4 * 8);
                v += bf2f((unsigned short)cv[0]) * xc[s4 * 4 + 0]
                   + bf2f((unsigned short)cv[1]) * xc[s4 * 4 + 1]
                   + bf2f((unsigned short)cv[2]) * xc[s4 * 4 + 2]
                   + bf2f((unsigned short)cv[3]) * xc[s4 * 4 + 3];
            }
            *(unsigned short*)(hsb + ((d * 512 + c * 2) ^ ((d & 7) << 4))) = f2bf(fmaxf(v, 0.f));
        }
    }
    __syncthreads();

    // ===== layers 2 and 3 =====
#pragma unroll 1
    for (int ly = 0; ly < 2; ++ly) {
        const unsigned short* WT = ly ? WTE3 : WTE2;
        const float* We_ = ly ? g3_We : g2_We;
        const float* ae_ = ly ? g3_ae : g2_ae;
        const float* bi_ = ly ? g3_b  : g2_b;

        if (tid < 8) {
            float s = 0.f;
            for (int c = 0; c < 32; ++c) s += We_[tid * 32 + c] * ae_[tid * 32 + c];
            sS[tid] = s;
        }

        // --- MFMA GEMM, K-split: wave w does kk = 4w..4w+3, 17 nt tiles ---
        {
            f32x4 acc[17];
#pragma unroll
            for (int nt = 0; nt < 17; ++nt) acc[nt] = (f32x4){0.f, 0.f, 0.f, 0.f};
            const int aswz = (arow & 7) << 4;
            const char* wt = (const char*)WT;
#pragma unroll
            for (int kq = 0; kq < 4; ++kq) {
                const int kk = w * 4 + kq;
                const int ab = arow * 512 + kk * 64 + kg * 8;
                const bf16x4 alo = *(const bf16x4*)(hsb + (ab ^ aswz));
                const bf16x4 ahi = *(const bf16x4*)(hsb + ((ab + 32) ^ aswz));
                const bf16x8 afrag = (bf16x8){alo[0], alo[1], alo[2], alo[3],
                                              ahi[0], ahi[1], ahi[2], ahi[3]};
#pragma unroll
                for (int nt = 0; nt < 17; ++nt) {
                    const char* bp = wt + (nt * 16 + arow) * 512 + kk * 64 + kg * 8;
                    const bf16x4 blo = *(const bf16x4*)(bp);
                    const bf16x4 bhi = *(const bf16x4*)(bp + 32);
                    const bf16x8 bfr = (bf16x8){blo[0], blo[1], blo[2], blo[3],
                                                bhi[0], bhi[1], bhi[2], bhi[3]};
                    acc[nt] = __builtin_amdgcn_mfma_f32_16x16x32_bf16(afrag, bfr, acc[nt], 0, 0, 0);
                }
            }
            if (w == 0) {
#pragma unroll
                for (int nt = 0; nt < 17; ++nt)
#pragma unroll
                    for (int r = 0; r < 4; ++r) xwp[kg * 4 + r][nt * 16 + arow] = acc[nt][r];
            }
            __syncthreads();
            if (w == 1) {
#pragma unroll
                for (int nt = 0; nt < 17; ++nt)
#pragma unroll
                    for (int r = 0; r < 4; ++r) xwp[kg * 4 + r][nt * 16 + arow] += acc[nt][r];
            }
            __syncthreads();
        }

        // --- softmax (self loop with eamean), 128 rows ---
        {
            const int d = tid >> 3, h = tid & 7;
            const float S = sS[h];
            const float aldv = xwp[d][264 + h];
            float alf[16];
            float m = -1e30f;
#pragma unroll
            for (int s = 0; s < 16; ++s) {
                float a;
                if (s == d) a = lrelu02(xwp[s][256 + h] + aldv + eamean * S);
                else {
                    const int el = s * 15 + d - (d > s ? 1 : 0);
                    a = lrelu02(xwp[s][256 + h] + aldv + ea[g * EPG + el] * S);
                }
                alf[s] = a;
                m = fmaxf(m, a);
            }
            float sum = 0.f;
#pragma unroll
            for (int s = 0; s < 16; ++s) { alf[s] = expf(alf[s] - m); sum += alf[s]; }
            const float r = 1.f / (sum + 1e-16f);
#pragma unroll
            for (int s = 0; s < 16; ++s) coefb[h][d][s] = f2bf(alf[s] * r);
        }
        __syncthreads();

        // --- aggregate via MFMA: wave w does nt = 8w..8w+7 ---
        {
#pragma unroll
            for (int nt2 = 0; nt2 < 8; ++nt2) {
                const int nt = w * 8 + nt2;
                const int h = nt >> 1;
                const int c2 = nt * 16 + arow;
                const bf16x4 alo = *(const bf16x4*)((const char*)coefb + h * 640 + arow * 40 + kg * 8);
                const bf16x8 afrag = (bf16x8){alo[0], alo[1], alo[2], alo[3], 0, 0, 0, 0};
                const bf16x8 bfr = (bf16x8){
                    (short)f2bf(xwp[kg * 4 + 0][c2]), (short)f2bf(xwp[kg * 4 + 1][c2]),
                    (short)f2bf(xwp[kg * 4 + 2][c2]), (short)f2bf(xwp[kg * 4 + 3][c2]),
                    0, 0, 0, 0};
                f32x4 hacc = __builtin_amdgcn_mfma_f32_16x16x32_bf16(
                                 afrag, bfr, (f32x4){0.f, 0.f, 0.f, 0.f}, 0, 0, 0);
                const float b = bi_[c2];
                float p = 0.f;
#pragma unroll
                for (int r = 0; r < 4; ++r) {
                    const float hv = fmaxf(hacc[r] + b, 0.f);
                    p += hv;
                    const int d = kg * 4 + r;
                    *(unsigned short*)(hsb + ((d * 512 + c2 * 2) ^ ((d & 7) << 4))) = f2bf(hv);
                }
                if (ly == 1) {
                    p += __shfl_xor(p, 16);
                    p += __shfl_xor(p, 32);
                    if (kg == 0) gembb[c2] = f2bf(p * (1.f / 16.f));
                }
            }
        }
        __syncthreads();
    }

    // ===== heads fc1 via MFMA: wave w does nt = 4w..4w+3 =====
    {
        f32x4 acc2[4];
#pragma unroll
        for (int nt2 = 0; nt2 < 4; ++nt2) acc2[nt2] = (f32x4){0.f, 0.f, 0.f, 0.f};
        const int aswz = (arow & 7) << 4;
        for (int kk = 0; kk < 16; ++kk) {
            bf16x4 alo, ahi;
            if (kk < 8) {
                const int ab = arow * 512 + kk * 64 + kg * 8;
                alo = *(const bf16x4*)(hsb + (ab ^ aswz));
                ahi = *(const bf16x4*)(hsb + ((ab + 32) ^ aswz));
            } else {
                const char* gp = (const char*)gembb + (kk - 8) * 64 + kg * 8;
                alo = *(const bf16x4*)(gp);
                ahi = *(const bf16x4*)(gp + 32);
            }
            const bf16x8 afrag = (bf16x8){alo[0], alo[1], alo[2], alo[3],
                                          ahi[0], ahi[1], ahi[2], ahi[3]};
#pragma unroll
            for (int nt2 = 0; nt2 < 4; ++nt2) {
                const int o = (w * 4 + nt2) * 16 + arow;
                const char* bp = (const char*)FT1 + o * 1024 + kk * 64 + kg * 8;
                const bf16x4 blo = *(const bf16x4*)(bp);
                const bf16x4 bhi = *(const bf16x4*)(bp + 32);
                const bf16x8 bfr = (bf16x8){blo[0], blo[1], blo[2], blo[3],
                                            bhi[0], bhi[1], bhi[2], bhi[3]};
                acc2[nt2] = __builtin_amdgcn_mfma_f32_16x16x32_bf16(afrag, bfr, acc2[nt2], 0, 0, 0);
            }
        }
#pragma unroll
        for (int nt2 = 0; nt2 < 4; ++nt2) {
            const int o = (w * 4 + nt2) * 16 + arow;
            const float wl0 = fc1W[o * 515 + 512];
            const float wl1 = fc1W[o * 515 + 513];
            const float wl2 = fc1W[o * 515 + 514];
            const float b   = fc1b[o];
#pragma unroll
            for (int r = 0; r < 4; ++r) {
                const int row = kg * 4 + r;
                if (row < 8) {
                    float v = acc2[nt2][r] + b
                            + lash[row][0] * wl0 + lash[row][1] * wl1 + lash[row][2] * wl2;
                    hidn[row][o] = fmaxf(v, 0.f);
                }
            }
        }
    }
    __syncthreads();

    // --- fc2 + output transforms ---
    if (tid < 48) {
        const int a = tid / 6, j = tid % 6;
        const float* wr = &fc2W[j * 128];
        float acc = fc2b[j];
#pragma unroll
        for (int k = 0; k < 128; ++k) acc += wr[k] * hidn[a][k];
        const int base = (g * 8 + a) * 3;
        if (j < 3) {
            const float lim = (j == 2) ? 3.1415927f : 1.0f;
            out[OUT_MEAN + base + j] = tanhf(acc) * lim;
        } else {
            const float sg = 1.f / (1.f + expf(-acc));
            out[OUT_STD + base + (j - 3)] = 0.01f + sg * (0.3f - 0.01f) + 1e-5f;
        }
    }
}

extern "C" void kernel_launch(void* const* d_in, const int* in_sizes, int n_in,
                              void* d_out, int out_size, void* d_ws, size_t ws_size,
                              hipStream_t stream)
{
    const float* x     = (const float*)d_in[0];
    const float* ea    = (const float*)d_in[2];
    const float* lc_w1 = (const float*)d_in[6];
    const float* lc_b1 = (const float*)d_in[7];
    const float* lc_w2 = (const float*)d_in[8];
    const float* lc_b2 = (const float*)d_in[9];
    const float* lc_wl = (const float*)d_in[10];
    const float* lc_bl = (const float*)d_in[11];
    const float* ld_w1 = (const float*)d_in[12];
    const float* ld_b1 = (const float*)d_in[13];
    const float* ld_w2 = (const float*)d_in[14];
    const float* ld_b2 = (const float*)d_in[15];
    const float* g1_W  = (const float*)d_in[16];
    const float* g1_as = (const float*)d_in[17];
    const float* g1_ad = (const float*)d_in[18];
    const float* g1_We = (const float*)d_in[19];
    const float* g1_ae = (const float*)d_in[20];
    const float* g1_b  = (const float*)d_in[21];
    const float* g2_W  = (const float*)d_in[22];
    const float* g2_as = (const float*)d_in[23];
    const float* g2_ad = (const float*)d_in[24];
    const float* g2_We = (const float*)d_in[25];
    const float* g2_ae = (const float*)d_in[26];
    const float* g2_b  = (const float*)d_in[27];
    const float* g3_W  = (const float*)d_in[28];
    const float* g3_as = (const float*)d_in[29];
    const float* g3_ad = (const float*)d_in[30];
    const float* g3_We = (const float*)d_in[31];
    const float* g3_ae = (const float*)d_in[32];
    const float* g3_b  = (const float*)d_in[33];
    const float* fc1_W = (const float*)d_in[34];
    const float* fc1_b = (const float*)d_in[35];
    const float* fc2_W = (const float*)d_in[36];
    const float* fc2_b = (const float*)d_in[37];

    float* out = (float*)d_out;
    unsigned short* WTE2 = (unsigned short*)d_ws;       // 272*256 bf16
    unsigned short* WTE3 = WTE2 + 272 * 256;
    unsigned short* FT1  = WTE3 + 272 * 256;            // 128*512 bf16
    float* W1E    = (float*)(FT1 + 128 * 512);          // 6*272 f32
    float* partial = W1E + 6 * 272;                     // 256 f32

    prep_kernel<<<2977, 256, 0, stream>>>(x, ea,
                                          g2_W, g2_as, g2_ad,
                                          g3_W, g3_as, g3_ad,
                                          g1_W, g1_as, g1_ad,
                                          fc1_W,
                                          lc_w1, lc_b1, lc_w2, lc_b2, lc_wl, lc_bl,
                                          ld_w1, ld_b1, ld_w2, ld_b2,
                                          WTE2, WTE3, W1E, FT1, partial, out);

    graph_kernel<<<NGRAPH, 128, 0, stream>>>(x, ea, partial,
                                             W1E, g1_We, g1_ae, g1_b,
                                             WTE2, g2_We, g2_ae, g2_b,
                                             WTE3, g3_We, g3_ae, g3_b,
                                             FT1, fc1_W, fc1_b, fc2_W, fc2_b, out);
}

// Round 14
// 102.449 us; speedup vs baseline: 1.7122x; 1.5656x over previous
//
#include <hip/hip_runtime.h>
#include <math.h>

#define NODES   16384
#define NGRAPH  1024
#define EDGES   245760
#define EPG     240
#define FDIM    256

#define OUT_MEAN  0
#define OUT_STD   24576
#define OUT_SCANS 49152
#define OUT_RECON 376832

typedef __attribute__((ext_vector_type(4))) short bf16x4;
typedef __attribute__((ext_vector_type(8))) short bf16x8;
typedef __attribute__((ext_vector_type(4))) float f32x4;

static __device__ __forceinline__ float lrelu02(float v){ return v > 0.f ? v : 0.2f*v; }

static __device__ __forceinline__ unsigned short f2bf(float f){
    unsigned u = __float_as_uint(f);
    u = (u + 0x7FFFu + ((u >> 16) & 1u)) >> 16;
    return (unsigned short)u;
}
static __device__ __forceinline__ float bf2f(unsigned short h){
    return __uint_as_float(((unsigned)h) << 16);
}

// ===== prep =====
// Fragment-ordered B layouts: for MFMA frag elem j, k = kk*32 + kg*4 + (j&3) + 16*(j>>2).
// WTEf[nt][kk][lane][8 bf16]: nt 0..16 (16 = folded als/ald cols), kk 0..7,
//   lane=(kg<<4)|arow, col = nt*16+arow.  8704 slots/matrix.
// FT1f[nt][kk][lane][8 bf16]: nt 0..7, kk 0..15, o = nt*16+arow. 8192 slots.
// blocks: [0,34) WTEf2 | [34,68) WTEf3 | [68,100) FT1f | 100 W1E |
//         [101,357) ea partials | [357,2405) lidar
__global__ __launch_bounds__(256) void prep_kernel(
    const float* __restrict__ x,  const float* __restrict__ ea,
    const float* __restrict__ W2, const float* __restrict__ as2, const float* __restrict__ ad2,
    const float* __restrict__ W3, const float* __restrict__ as3, const float* __restrict__ ad3,
    const float* __restrict__ W1, const float* __restrict__ as1, const float* __restrict__ ad1,
    const float* __restrict__ F1,
    const float* __restrict__ w1, const float* __restrict__ b1,
    const float* __restrict__ w2, const float* __restrict__ b2,
    const float* __restrict__ wl, const float* __restrict__ bl,
    const float* __restrict__ dw1, const float* __restrict__ db1,
    const float* __restrict__ dw2, const float* __restrict__ db2,
    unsigned short* __restrict__ T2, unsigned short* __restrict__ T3,
    unsigned short* __restrict__ T1, float* __restrict__ W1E,
    float* __restrict__ partial, float* __restrict__ out)
{
    __shared__ float red[256];
    __shared__ float sc[8][25];
    __shared__ float pooled[8][160];
    __shared__ float hid_lds[8][32];

    const int b = blockIdx.x;
    const int tid = threadIdx.x;

    if (b < 68) {
        const float* W   = (b < 34) ? W2 : W3;
        const float* as_ = (b < 34) ? as2 : as3;
        const float* ad_ = (b < 34) ? ad2 : ad3;
        unsigned short* T = (b < 34) ? T2 : T3;
        const int slot = ((b < 34) ? b : b - 34) * 256 + tid;
        const int nt = slot >> 9;
        const int rem = slot & 511;
        const int kk = rem >> 6;
        const int lane = rem & 63;
        const int ar = lane & 15, kgg = lane >> 4;
        const int col = nt * 16 + ar;
        unsigned short vals[8];
#pragma unroll
        for (int j = 0; j < 8; ++j) {
            const int k = kk * 32 + kgg * 4 + (j & 3) + ((j >> 2) << 4);
            float v;
            if (col < 256) v = W[k * 256 + col];
            else {
                const int j2 = col - 256, h = j2 & 7;
                const float* av = (j2 < 8) ? as_ : ad_;
                float s = 0.f;
                for (int c = 0; c < 32; ++c) s += W[k * 256 + h * 32 + c] * av[h * 32 + c];
                v = s;
            }
            vals[j] = f2bf(v);
        }
        *(bf16x8*)(T + (size_t)slot * 8) = *(const bf16x8*)vals;
        return;
    }
    if (b < 100) {
        const int slot = (b - 68) * 256 + tid;
        const int nt = slot >> 10;
        const int rem = slot & 1023;
        const int kk = rem >> 6;
        const int lane = rem & 63;
        const int o = nt * 16 + (lane & 15);
        const int kgg = lane >> 4;
        unsigned short vals[8];
#pragma unroll
        for (int j = 0; j < 8; ++j) {
            const int k = kk * 32 + kgg * 4 + (j & 3) + ((j >> 2) << 4);
            vals[j] = f2bf(F1[o * 515 + k]);
        }
        *(bf16x8*)(T1 + (size_t)slot * 8) = *(const bf16x8*)vals;
        return;
    }
    if (b == 100) {
        for (int c = tid; c < 272; c += 256) {
            for (int k = 0; k < 6; ++k) {
                float v;
                if (c < 256) v = W1[k * 256 + c];
                else {
                    const int j = c - 256, h = j & 7;
                    const float* av = (j < 8) ? as1 : ad1;
                    float s = 0.f;
                    for (int cc = 0; cc < 32; ++cc) s += W1[k * 256 + h * 32 + cc] * av[h * 32 + cc];
                    v = s;
                }
                W1E[k * 272 + c] = v;
            }
        }
        return;
    }
    if (b < 357) {
        const int base = (b - 101) * 960;
        float s = 0.f;
        for (int i = tid; i < 960; i += 256) s += ea[base + i];
        red[tid] = s; __syncthreads();
        for (int off = 128; off > 0; off >>= 1) {
            if (tid < off) red[tid] += red[tid + off];
            __syncthreads();
        }
        if (tid == 0) partial[b - 101] = red[0];
        return;
    }

    // ---- lidar (verified body) ----
    const int lane = tid & 31;
    const int nl   = tid >> 5;
    const int n    = (b - 357) * 8 + nl;

    if (lane < 20) {
        const float v = x[n * 29 + lane];
        sc[nl][lane + 2] = v;
        out[OUT_SCANS + n * 20 + lane] = v;
    } else if (lane < 25) {
        const int pads[5] = {0, 1, 22, 23, 24};
        sc[nl][pads[lane - 20]] = 0.f;
    }
    __syncthreads();

    {
        const int ic = lane & 15;
        const int hi = lane >> 4;
        float w1r[5];
#pragma unroll
        for (int k = 0; k < 5; ++k) w1r[k] = w1[ic * 5 + k];
        const float b1r = b1[ic];
#pragma unroll
        for (int q = 0; q < 5; ++q) {
            const int u  = 2 * q + hi;
            const int p0 = 2 * u;
            float a = b1r, bb = b1r;
#pragma unroll
            for (int k = 0; k < 5; ++k) {
                a  += sc[nl][p0 + k] * w1r[k];
                bb += sc[nl][p0 + 1 + k] * w1r[k];
            }
            pooled[nl][u * 16 + ic] = fmaxf(fmaxf(a, bb), 0.f);
        }
    }
    __syncthreads();

    float macc = 0.f;
    {
        float wreg[48];
#pragma unroll
        for (int i = 0; i < 12; ++i) {
            const float4 v4 = *(const float4*)&w2[lane * 48 + i * 4];
            wreg[i * 4 + 0] = v4.x; wreg[i * 4 + 1] = v4.y;
            wreg[i * 4 + 2] = v4.z; wreg[i * 4 + 3] = v4.w;
        }
        const float b2r = b2[lane];
        float pc[3][16];
#pragma unroll
        for (int i = 0; i < 4; ++i) {
            const float4 v0 = *(const float4*)&pooled[nl][0 * 16 + i * 4];
            const float4 v1 = *(const float4*)&pooled[nl][1 * 16 + i * 4];
            pc[0][i * 4 + 0] = v0.x; pc[0][i * 4 + 1] = v0.y; pc[0][i * 4 + 2] = v0.z; pc[0][i * 4 + 3] = v0.w;
            pc[1][i * 4 + 0] = v1.x; pc[1][i * 4 + 1] = v1.y; pc[1][i * 4 + 2] = v1.z; pc[1][i * 4 + 3] = v1.w;
            pc[2][i * 4 + 0] = 0.f;  pc[2][i * 4 + 1] = 0.f;  pc[2][i * 4 + 2] = 0.f;  pc[2][i * 4 + 3] = 0.f;
        }
#pragma unroll
        for (int t = 0; t < 10; ++t) {
            const int prev = (t + 2) % 3, cur = t % 3, nxt = (t + 1) % 3;
            if (t >= 1) {
                if (t + 1 <= 9) {
#pragma unroll
                    for (int i = 0; i < 4; ++i) {
                        const float4 v4 = *(const float4*)&pooled[nl][(t + 1) * 16 + i * 4];
                        pc[nxt][i * 4 + 0] = v4.x; pc[nxt][i * 4 + 1] = v4.y;
                        pc[nxt][i * 4 + 2] = v4.z; pc[nxt][i * 4 + 3] = v4.w;
                    }
                } else {
#pragma unroll
                    for (int ic = 0; ic < 16; ++ic) pc[nxt][ic] = 0.f;
                }
            }
            float v = b2r;
#pragma unroll
            for (int ic = 0; ic < 16; ++ic) {
                v += pc[prev][ic] * wreg[ic * 3 + 0]
                   + pc[cur][ic]  * wreg[ic * 3 + 1]
                   + pc[nxt][ic]  * wreg[ic * 3 + 2];
            }
            macc += fmaxf(v, 0.f);
        }
    }

    const float feat = macc * 0.1f;
    float z[5];
#pragma unroll
    for (int j = 0; j < 5; ++j) {
        float p = feat * wl[j * 32 + lane];
        p += __shfl_xor(p, 1);
        p += __shfl_xor(p, 2);
        p += __shfl_xor(p, 4);
        p += __shfl_xor(p, 8);
        p += __shfl_xor(p, 16);
        z[j] = fmaxf(bl[j] + p, 0.f);
    }
    float hv = db1[lane];
#pragma unroll
    for (int j = 0; j < 5; ++j) hv += z[j] * dw1[lane * 5 + j];
    hid_lds[nl][lane] = fmaxf(hv, 0.f);
    __syncthreads();

    if (lane < 20) {
        float acc = db2[lane];
#pragma unroll
        for (int k = 0; k < 32; ++k) acc += hid_lds[nl][k] * dw2[lane * 32 + k];
        out[OUT_RECON + n * 20 + lane] = acc;
    }
}

// ===== per-graph-pair kernel: 512 blocks x 256 threads (4 waves), 2 graphs =
// GEMM: nt-split across waves (full K per wave, no partial sums); aggregate
// B-frags come from the wave's own GEMM registers. Only als/ald cols hit LDS.
__global__ __launch_bounds__(256) void graph_kernel(
    const float* __restrict__ x,   const float* __restrict__ ea,
    const float* __restrict__ partial,
    const float* __restrict__ W1E,
    const float* __restrict__ g1_We, const float* __restrict__ g1_ae,
    const float* __restrict__ g1_b,
    const unsigned short* __restrict__ WTEf2,
    const float* __restrict__ g2_We, const float* __restrict__ g2_ae,
    const float* __restrict__ g2_b,
    const unsigned short* __restrict__ WTEf3,
    const float* __restrict__ g3_We, const float* __restrict__ g3_ae,
    const float* __restrict__ g3_b,
    const unsigned short* __restrict__ FT1f,
    const float* __restrict__ fc1W, const float* __restrict__ fc1b,
    const float* __restrict__ fc2W, const float* __restrict__ fc2b,
    float* __restrict__ out)
{
    __shared__ char hsb[2][8192] __attribute__((aligned(16)));
    __shared__ float salsald[2][16][16];
    __shared__ unsigned short coefb[2][8][16][20] __attribute__((aligned(8)));
    __shared__ float sS[8];
    __shared__ float hs6[2][16][6];
    __shared__ float lash[2][8][3];
    __shared__ float hidn[16][132];
    __shared__ unsigned short gembb[2][256] __attribute__((aligned(8)));

    const int tid = threadIdx.x;
    const int g0 = blockIdx.x * 2;
    const int lane = tid & 63, w = tid >> 6;
    const int arow = lane & 15, kg = lane >> 4;

    // --- edge-attr mean (per-wave butterfly) ---
    float eamean;
    {
        float pv = partial[lane] + partial[lane + 64] + partial[lane + 128] + partial[lane + 192];
        pv += __shfl_xor(pv, 1);
        pv += __shfl_xor(pv, 2);
        pv += __shfl_xor(pv, 4);
        pv += __shfl_xor(pv, 8);
        pv += __shfl_xor(pv, 16);
        pv += __shfl_xor(pv, 32);
        eamean = pv * (1.f / (float)EDGES);
    }

    // --- stage inputs ---
    if (tid < 192) {
        const int gg = tid / 96, t = tid % 96;
        hs6[gg][t / 6][t % 6] = x[((g0 + gg) * 16 + t / 6) * 29 + 20 + t % 6];
    } else if (tid < 240) {
        const int t = tid - 192, gg = t / 24, r = t % 24;
        lash[gg][r / 3][r % 3] = x[((g0 + gg) * 16 + r / 3) * 29 + 26 + r % 3];
    }
    if (tid < 8) {
        float s = 0.f;
        for (int c = 0; c < 32; ++c) s += g1_We[tid * 32 + c] * g1_ae[tid * 32 + c];
        sS[tid] = s;
    }
    __syncthreads();

    // ===== L1: both graphs in parallel (gg = tid>>7, ht = tid&127) =====
    {
        const int gg = tid >> 7, ht = tid & 127;
        float colA[16], colB[16];
#pragma unroll
        for (int i = 0; i < 16; ++i) { colA[i] = 0.f; colB[i] = 0.f; }
#pragma unroll
        for (int k = 0; k < 6; ++k) {
            const float wa = W1E[k * 272 + ht];
            const float wb = W1E[k * 272 + ht + 128];
#pragma unroll
            for (int i = 0; i < 16; ++i) {
                const float hv = hs6[gg][i][k];
                colA[i] += hv * wa;
                colB[i] += hv * wb;
            }
        }
        if (ht < 16) {
            float colC[16];
#pragma unroll
            for (int i = 0; i < 16; ++i) colC[i] = 0.f;
#pragma unroll
            for (int k = 0; k < 6; ++k) {
                const float wc = W1E[k * 272 + 256 + ht];
#pragma unroll
                for (int i = 0; i < 16; ++i) colC[i] += hs6[gg][i][k] * wc;
            }
#pragma unroll
            for (int i = 0; i < 16; ++i) salsald[gg][i][ht] = colC[i];
        }
        __syncthreads();

        // L1 softmax (no self loop)
        {
            const int d = ht >> 3, h = ht & 7;
            const float S = sS[h];
            const float aldv = salsald[gg][d][8 + h];
            float alf[16];
            float m = -1e30f;
#pragma unroll
            for (int s = 0; s < 16; ++s) {
                float a;
                if (s == d) a = -1e30f;
                else {
                    const int el = s * 15 + d - (d > s ? 1 : 0);
                    a = lrelu02(salsald[gg][s][h] + aldv + ea[(g0 + gg) * EPG + el] * S);
                }
                alf[s] = a;
                m = fmaxf(m, a);
            }
            float sum = 0.f;
#pragma unroll
            for (int s = 0; s < 16; ++s) { alf[s] = expf(alf[s] - m); sum += alf[s]; }
            const float r = 1.f / (sum + 1e-16f);
#pragma unroll
            for (int s = 0; s < 16; ++s) coefb[gg][h][d][s] = f2bf(alf[s] * r);
        }
        __syncthreads();

        // L1 aggregate from register columns
#pragma unroll
        for (int cc = 0; cc < 2; ++cc) {
            const int c = ht + cc * 128;
            const int h = c >> 5;
            const float b = g1_b[c];
            const float* xc = cc ? colB : colA;
#pragma unroll
            for (int d = 0; d < 16; ++d) {
                float v = b;
#pragma unroll
                for (int s4 = 0; s4 < 4; ++s4) {
                    const bf16x4 cv = *(const bf16x4*)((const char*)&coefb[gg][0][0][0] + h * 640 + d * 40 + s4 * 8);
                    v += bf2f((unsigned short)cv[0]) * xc[s4 * 4 + 0]
                       + bf2f((unsigned short)cv[1]) * xc[s4 * 4 + 1]
                       + bf2f((unsigned short)cv[2]) * xc[s4 * 4 + 2]
                       + bf2f((unsigned short)cv[3]) * xc[s4 * 4 + 3];
                }
                *(unsigned short*)(hsb[gg] + ((d * 512 + c * 2) ^ ((d & 7) << 4))) = f2bf(fmaxf(v, 0.f));
            }
        }
    }
    __syncthreads();

    // ===== layers 2 and 3 =====
#pragma unroll 1
    for (int ly = 0; ly < 2; ++ly) {
        const unsigned short* WT = ly ? WTEf3 : WTEf2;
        const float* We_ = ly ? g3_We : g2_We;
        const float* ae_ = ly ? g3_ae : g2_ae;
        const float* bi_ = ly ? g3_b  : g2_b;

        if (tid < 8) {
            float s = 0.f;
            for (int c = 0; c < 32; ++c) s += We_[tid * 32 + c] * ae_[tid * 32 + c];
            sS[tid] = s;
        }

        // --- GEMM: wave w owns nt = 4t+w (t=0..4, nt<=16), full K, 2 graphs ---
        f32x4 acc[5][2];
#pragma unroll
        for (int t = 0; t < 5; ++t) { acc[t][0] = (f32x4){0,0,0,0}; acc[t][1] = (f32x4){0,0,0,0}; }
        {
            const int aswz = (arow & 7) << 4;
            for (int kk = 0; kk < 8; ++kk) {
                bf16x8 afr[2];
#pragma unroll
                for (int gg = 0; gg < 2; ++gg) {
                    const int ab = arow * 512 + kk * 64 + kg * 8;
                    const bf16x4 alo = *(const bf16x4*)(hsb[gg] + (ab ^ aswz));
                    const bf16x4 ahi = *(const bf16x4*)(hsb[gg] + ((ab + 32) ^ aswz));
                    afr[gg] = (bf16x8){alo[0], alo[1], alo[2], alo[3],
                                       ahi[0], ahi[1], ahi[2], ahi[3]};
                }
#pragma unroll
                for (int t = 0; t < 5; ++t) {
                    const int nt = 4 * t + w;
                    if (nt <= 16) {
                        const bf16x8 bfr = *(const bf16x8*)(WT + (size_t)((nt * 8 + kk) * 64 + lane) * 8);
                        acc[t][0] = __builtin_amdgcn_mfma_f32_16x16x32_bf16(afr[0], bfr, acc[t][0], 0, 0, 0);
                        acc[t][1] = __builtin_amdgcn_mfma_f32_16x16x32_bf16(afr[1], bfr, acc[t][1], 0, 0, 0);
                    }
                }
            }
        }
        // nt==16 (wave 0, t=4) -> als/ald to LDS
        if (w == 0) {
#pragma unroll
            for (int gg = 0; gg < 2; ++gg)
#pragma unroll
                for (int r = 0; r < 4; ++r) salsald[gg][kg * 4 + r][arow] = acc[4][gg][r];
        }
        __syncthreads();

        // --- softmax: 256 rows (gg = tid>>7, row = tid&127) ---
        {
            const int gg = tid >> 7, row = tid & 127;
            const int d = row >> 3, h = row & 7;
            const float S = sS[h];
            const float aldv = salsald[gg][d][8 + h];
            float alf[16];
            float m = -1e30f;
#pragma unroll
            for (int s = 0; s < 16; ++s) {
                float a;
                if (s == d) a = lrelu02(salsald[gg][s][h] + aldv + eamean * S);
                else {
                    const int el = s * 15 + d - (d > s ? 1 : 0);
                    a = lrelu02(salsald[gg][s][h] + aldv + ea[(g0 + gg) * EPG + el] * S);
                }
                alf[s] = a;
                m = fmaxf(m, a);
            }
            float sum = 0.f;
#pragma unroll
            for (int s = 0; s < 16; ++s) { alf[s] = expf(alf[s] - m); sum += alf[s]; }
            const float r = 1.f / (sum + 1e-16f);
#pragma unroll
            for (int s = 0; s < 16; ++s) coefb[gg][h][d][s] = f2bf(alf[s] * r);
        }
        __syncthreads();

        // --- aggregate via MFMA from own GEMM regs (nt<16) ---
        {
#pragma unroll
            for (int t = 0; t < 4; ++t) {
                const int nt = 4 * t + w;
                const int h = nt >> 1;
                const int c2 = nt * 16 + arow;
#pragma unroll
                for (int gg = 0; gg < 2; ++gg) {
                    const bf16x4 alo = *(const bf16x4*)((const char*)&coefb[gg][0][0][0] + h * 640 + arow * 40 + kg * 8);
                    const bf16x8 afrag = (bf16x8){alo[0], alo[1], alo[2], alo[3], 0, 0, 0, 0};
                    const bf16x8 bfr = (bf16x8){
                        (short)f2bf(acc[t][gg][0]), (short)f2bf(acc[t][gg][1]),
                        (short)f2bf(acc[t][gg][2]), (short)f2bf(acc[t][gg][3]),
                        0, 0, 0, 0};
                    f32x4 hacc = __builtin_amdgcn_mfma_f32_16x16x32_bf16(
                                     afrag, bfr, (f32x4){0.f, 0.f, 0.f, 0.f}, 0, 0, 0);
                    const float b = bi_[c2];
                    float p = 0.f;
#pragma unroll
                    for (int r = 0; r < 4; ++r) {
                        const float hv = fmaxf(hacc[r] + b, 0.f);
                        p += hv;
                        const int d = kg * 4 + r;
                        *(unsigned short*)(hsb[gg] + ((d * 512 + c2 * 2) ^ ((d & 7) << 4))) = f2bf(hv);
                    }
                    if (ly == 1) {
                        p += __shfl_xor(p, 16);
                        p += __shfl_xor(p, 32);
                        if (kg == 0) gembb[gg][c2] = f2bf(p * (1.f / 16.f));
                    }
                }
            }
        }
        __syncthreads();
    }

    // ===== fc1 via MFMA: M=16 agent rows (2 graphs x 8), wave w: 2 nt =====
    {
        f32x4 acc2[2];
        acc2[0] = (f32x4){0,0,0,0};
        acc2[1] = (f32x4){0,0,0,0};
        const int agg = arow >> 3, alr = arow & 7;      // A-row -> (graph, node)
        const int aswz = (alr & 7) << 4;
        for (int kk = 0; kk < 16; ++kk) {
            bf16x4 alo, ahi;
            if (kk < 8) {
                const int ab = alr * 512 + kk * 64 + kg * 8;
                alo = *(const bf16x4*)(hsb[agg] + (ab ^ aswz));
                ahi = *(const bf16x4*)(hsb[agg] + ((ab + 32) ^ aswz));
            } else {
                const char* gp = (const char*)&gembb[agg][0] + (kk - 8) * 64 + kg * 8;
                alo = *(const bf16x4*)(gp);
                ahi = *(const bf16x4*)(gp + 32);
            }
            const bf16x8 afrag = (bf16x8){alo[0], alo[1], alo[2], alo[3],
                                          ahi[0], ahi[1], ahi[2], ahi[3]};
#pragma unroll
            for (int nt2 = 0; nt2 < 2; ++nt2) {
                const int nt = w * 2 + nt2;
                const bf16x8 bfr = *(const bf16x8*)(FT1f + (size_t)((nt * 16 + kk) * 64 + lane) * 8);
                acc2[nt2] = __builtin_amdgcn_mfma_f32_16x16x32_bf16(afrag, bfr, acc2[nt2], 0, 0, 0);
            }
        }
#pragma unroll
        for (int nt2 = 0; nt2 < 2; ++nt2) {
            const int o = (w * 2 + nt2) * 16 + arow;
            const float wl0 = fc1W[o * 515 + 512];
            const float wl1 = fc1W[o * 515 + 513];
            const float wl2 = fc1W[o * 515 + 514];
            const float b   = fc1b[o];
#pragma unroll
            for (int r = 0; r < 4; ++r) {
                const int row = kg * 4 + r;          // 0..15: gg=row>>3, agent=row&7
                const int gg = row >> 3, ag = row & 7;
                float v = acc2[nt2][r] + b
                        + lash[gg][ag][0] * wl0 + lash[gg][ag][1] * wl1 + lash[gg][ag][2] * wl2;
                hidn[row][o] = fmaxf(v, 0.f);
            }
        }
    }
    __syncthreads();

    // --- fc2 + output transforms (16 agents x 6) ---
    if (tid < 96) {
        const int a = tid / 6, j = tid % 6;
        const float* wr = &fc2W[j * 128];
        float acc = fc2b[j];
#pragma unroll
        for (int k = 0; k < 128; ++k) acc += wr[k] * hidn[a][k];
        const int gg = a >> 3, ag = a & 7;
        const int base = ((g0 + gg) * 8 + ag) * 3;
        if (j < 3) {
            const float lim = (j == 2) ? 3.1415927f : 1.0f;
            out[OUT_MEAN + base + j] = tanhf(acc) * lim;
        } else {
            const float sg = 1.f / (1.f + expf(-acc));
            out[OUT_STD + base + (j - 3)] = 0.01f + sg * (0.3f - 0.01f) + 1e-5f;
        }
    }
}

extern "C" void kernel_launch(void* const* d_in, const int* in_sizes, int n_in,
                              void* d_out, int out_size, void* d_ws, size_t ws_size,
                              hipStream_t stream)
{
    const float* x     = (const float*)d_in[0];
    const float* ea    = (const float*)d_in[2];
    const float* lc_w1 = (const float*)d_in[6];
    const float* lc_b1 = (const float*)d_in[7];
    const float* lc_w2 = (const float*)d_in[8];
    const float* lc_b2 = (const float*)d_in[9];
    const float* lc_wl = (const float*)d_in[10];
    const float* lc_bl = (const float*)d_in[11];
    const float* ld_w1 = (const float*)d_in[12];
    const float* ld_b1 = (const float*)d_in[13];
    const float* ld_w2 = (const float*)d_in[14];
    const float* ld_b2 = (const float*)d_in[15];
    const float* g1_W  = (const float*)d_in[16];
    const float* g1_as = (const float*)d_in[17];
    const float* g1_ad = (const float*)d_in[18];
    const float* g1_We = (const float*)d_in[19];
    const float* g1_ae = (const float*)d_in[20];
    const float* g1_b  = (const float*)d_in[21];
    const float* g2_W  = (const float*)d_in[22];
    const float* g2_as = (const float*)d_in[23];
    const float* g2_ad = (const float*)d_in[24];
    const float* g2_We = (const float*)d_in[25];
    const float* g2_ae = (const float*)d_in[26];
    const float* g2_b  = (const float*)d_in[27];
    const float* g3_W  = (const float*)d_in[28];
    const float* g3_as = (const float*)d_in[29];
    const float* g3_ad = (const float*)d_in[30];
    const float* g3_We = (const float*)d_in[31];
    const float* g3_ae = (const float*)d_in[32];
    const float* g3_b  = (const float*)d_in[33];
    const float* fc1_W = (const float*)d_in[34];
    const float* fc1_b = (const float*)d_in[35];
    const float* fc2_W = (const float*)d_in[36];
    const float* fc2_b = (const float*)d_in[37];

    float* out = (float*)d_out;
    unsigned short* WTEf2 = (unsigned short*)d_ws;        // 8704*8 bf16
    unsigned short* WTEf3 = WTEf2 + 8704 * 8;
    unsigned short* FT1f  = WTEf3 + 8704 * 8;             // 8192*8 bf16
    float* W1E    = (float*)(FT1f + 8192 * 8);            // 6*272 f32
    float* partial = W1E + 6 * 272;                       // 256 f32

    prep_kernel<<<2405, 256, 0, stream>>>(x, ea,
                                          g2_W, g2_as, g2_ad,
                                          g3_W, g3_as, g3_ad,
                                          g1_W, g1_as, g1_ad,
                                          fc1_W,
                                          lc_w1, lc_b1, lc_w2, lc_b2, lc_wl, lc_bl,
                                          ld_w1, ld_b1, ld_w2, ld_b2,
                                          WTEf2, WTEf3, FT1f, W1E, partial, out);

    graph_kernel<<<512, 256, 0, stream>>>(x, ea, partial,
                                          W1E, g1_We, g1_ae, g1_b,
                                          WTEf2, g2_We, g2_ae, g2_b,
                                          WTEf3, g3_We, g3_ae, g3_b,
                                          FT1f, fc1_W, fc1_b, fc2_W, fc2_b, out);
}

// Round 17
// 73.506 us; speedup vs baseline: 2.3864x; 1.3938x over previous
//
#include <hip/hip_runtime.h>
#include <math.h>

#define NODES   16384
#define NGRAPH  1024
#define EDGES   245760
#define EPG     240
#define FDIM    256

#define OUT_MEAN  0
#define OUT_STD   24576
#define OUT_SCANS 49152
#define OUT_RECON 376832

typedef __attribute__((ext_vector_type(4))) short bf16x4;
typedef __attribute__((ext_vector_type(8))) short bf16x8;
typedef __attribute__((ext_vector_type(4))) float f32x4;

static __device__ __forceinline__ float lrelu02(float v){ return v > 0.f ? v : 0.2f*v; }

static __device__ __forceinline__ unsigned short f2bf(float f){
    unsigned u = __float_as_uint(f);
    u = (u + 0x7FFFu + ((u >> 16) & 1u)) >> 16;
    return (unsigned short)u;
}
static __device__ __forceinline__ float bf2f(unsigned short h){
    return __uint_as_float(((unsigned)h) << 16);
}

// ===== prep (unchanged, verified) =====
__global__ __launch_bounds__(256) void prep_kernel(
    const float* __restrict__ x,  const float* __restrict__ ea,
    const float* __restrict__ W2, const float* __restrict__ as2, const float* __restrict__ ad2,
    const float* __restrict__ W3, const float* __restrict__ as3, const float* __restrict__ ad3,
    const float* __restrict__ W1, const float* __restrict__ as1, const float* __restrict__ ad1,
    const float* __restrict__ F1,
    const float* __restrict__ w1, const float* __restrict__ b1,
    const float* __restrict__ w2, const float* __restrict__ b2,
    const float* __restrict__ wl, const float* __restrict__ bl,
    const float* __restrict__ dw1, const float* __restrict__ db1,
    const float* __restrict__ dw2, const float* __restrict__ db2,
    unsigned short* __restrict__ T2, unsigned short* __restrict__ T3,
    unsigned short* __restrict__ T1, float* __restrict__ W1E,
    float* __restrict__ partial, float* __restrict__ out)
{
    __shared__ float red[256];
    __shared__ float sc[8][25];
    __shared__ float pooled[8][160];
    __shared__ float hid_lds[8][32];

    const int b = blockIdx.x;
    const int tid = threadIdx.x;

    if (b < 68) {
        const float* W   = (b < 34) ? W2 : W3;
        const float* as_ = (b < 34) ? as2 : as3;
        const float* ad_ = (b < 34) ? ad2 : ad3;
        unsigned short* T = (b < 34) ? T2 : T3;
        const int slot = ((b < 34) ? b : b - 34) * 256 + tid;
        const int nt = slot >> 9;
        const int rem = slot & 511;
        const int kk = rem >> 6;
        const int lane = rem & 63;
        const int ar = lane & 15, kgg = lane >> 4;
        const int col = nt * 16 + ar;
        unsigned short vals[8];
#pragma unroll
        for (int j = 0; j < 8; ++j) {
            const int k = kk * 32 + kgg * 4 + (j & 3) + ((j >> 2) << 4);
            float v;
            if (col < 256) v = W[k * 256 + col];
            else {
                const int j2 = col - 256, h = j2 & 7;
                const float* av = (j2 < 8) ? as_ : ad_;
                float s = 0.f;
                for (int c = 0; c < 32; ++c) s += W[k * 256 + h * 32 + c] * av[h * 32 + c];
                v = s;
            }
            vals[j] = f2bf(v);
        }
        *(bf16x8*)(T + (size_t)slot * 8) = *(const bf16x8*)vals;
        return;
    }
    if (b < 100) {
        const int slot = (b - 68) * 256 + tid;
        const int nt = slot >> 10;
        const int rem = slot & 1023;
        const int kk = rem >> 6;
        const int lane = rem & 63;
        const int o = nt * 16 + (lane & 15);
        const int kgg = lane >> 4;
        unsigned short vals[8];
#pragma unroll
        for (int j = 0; j < 8; ++j) {
            const int k = kk * 32 + kgg * 4 + (j & 3) + ((j >> 2) << 4);
            vals[j] = f2bf(F1[o * 515 + k]);
        }
        *(bf16x8*)(T1 + (size_t)slot * 8) = *(const bf16x8*)vals;
        return;
    }
    if (b == 100) {
        for (int c = tid; c < 272; c += 256) {
            for (int k = 0; k < 6; ++k) {
                float v;
                if (c < 256) v = W1[k * 256 + c];
                else {
                    const int j = c - 256, h = j & 7;
                    const float* av = (j < 8) ? as1 : ad1;
                    float s = 0.f;
                    for (int cc = 0; cc < 32; ++cc) s += W1[k * 256 + h * 32 + cc] * av[h * 32 + cc];
                    v = s;
                }
                W1E[k * 272 + c] = v;
            }
        }
        return;
    }
    if (b < 357) {
        const int base = (b - 101) * 960;
        float s = 0.f;
        for (int i = tid; i < 960; i += 256) s += ea[base + i];
        red[tid] = s; __syncthreads();
        for (int off = 128; off > 0; off >>= 1) {
            if (tid < off) red[tid] += red[tid + off];
            __syncthreads();
        }
        if (tid == 0) partial[b - 101] = red[0];
        return;
    }

    // ---- lidar (verified body) ----
    const int lane = tid & 31;
    const int nl   = tid >> 5;
    const int n    = (b - 357) * 8 + nl;

    if (lane < 20) {
        const float v = x[n * 29 + lane];
        sc[nl][lane + 2] = v;
        out[OUT_SCANS + n * 20 + lane] = v;
    } else if (lane < 25) {
        const int pads[5] = {0, 1, 22, 23, 24};
        sc[nl][pads[lane - 20]] = 0.f;
    }
    __syncthreads();

    {
        const int ic = lane & 15;
        const int hi = lane >> 4;
        float w1r[5];
#pragma unroll
        for (int k = 0; k < 5; ++k) w1r[k] = w1[ic * 5 + k];
        const float b1r = b1[ic];
#pragma unroll
        for (int q = 0; q < 5; ++q) {
            const int u  = 2 * q + hi;
            const int p0 = 2 * u;
            float a = b1r, bb = b1r;
#pragma unroll
            for (int k = 0; k < 5; ++k) {
                a  += sc[nl][p0 + k] * w1r[k];
                bb += sc[nl][p0 + 1 + k] * w1r[k];
            }
            pooled[nl][u * 16 + ic] = fmaxf(fmaxf(a, bb), 0.f);
        }
    }
    __syncthreads();

    float macc = 0.f;
    {
        float wreg[48];
#pragma unroll
        for (int i = 0; i < 12; ++i) {
            const float4 v4 = *(const float4*)&w2[lane * 48 + i * 4];
            wreg[i * 4 + 0] = v4.x; wreg[i * 4 + 1] = v4.y;
            wreg[i * 4 + 2] = v4.z; wreg[i * 4 + 3] = v4.w;
        }
        const float b2r = b2[lane];
        float pc[3][16];
#pragma unroll
        for (int i = 0; i < 4; ++i) {
            const float4 v0 = *(const float4*)&pooled[nl][0 * 16 + i * 4];
            const float4 v1 = *(const float4*)&pooled[nl][1 * 16 + i * 4];
            pc[0][i * 4 + 0] = v0.x; pc[0][i * 4 + 1] = v0.y; pc[0][i * 4 + 2] = v0.z; pc[0][i * 4 + 3] = v0.w;
            pc[1][i * 4 + 0] = v1.x; pc[1][i * 4 + 1] = v1.y; pc[1][i * 4 + 2] = v1.z; pc[1][i * 4 + 3] = v1.w;
            pc[2][i * 4 + 0] = 0.f;  pc[2][i * 4 + 1] = 0.f;  pc[2][i * 4 + 2] = 0.f;  pc[2][i * 4 + 3] = 0.f;
        }
#pragma unroll
        for (int t = 0; t < 10; ++t) {
            const int prev = (t + 2) % 3, cur = t % 3, nxt = (t + 1) % 3;
            if (t >= 1) {
                if (t + 1 <= 9) {
#pragma unroll
                    for (int i = 0; i < 4; ++i) {
                        const float4 v4 = *(const float4*)&pooled[nl][(t + 1) * 16 + i * 4];
                        pc[nxt][i * 4 + 0] = v4.x; pc[nxt][i * 4 + 1] = v4.y;
                        pc[nxt][i * 4 + 2] = v4.z; pc[nxt][i * 4 + 3] = v4.w;
                    }
                } else {
#pragma unroll
                    for (int ic = 0; ic < 16; ++ic) pc[nxt][ic] = 0.f;
                }
            }
            float v = b2r;
#pragma unroll
            for (int ic = 0; ic < 16; ++ic) {
                v += pc[prev][ic] * wreg[ic * 3 + 0]
                   + pc[cur][ic]  * wreg[ic * 3 + 1]
                   + pc[nxt][ic]  * wreg[ic * 3 + 2];
            }
            macc += fmaxf(v, 0.f);
        }
    }

    const float feat = macc * 0.1f;
    float z[5];
#pragma unroll
    for (int j = 0; j < 5; ++j) {
        float p = feat * wl[j * 32 + lane];
        p += __shfl_xor(p, 1);
        p += __shfl_xor(p, 2);
        p += __shfl_xor(p, 4);
        p += __shfl_xor(p, 8);
        p += __shfl_xor(p, 16);
        z[j] = fmaxf(bl[j] + p, 0.f);
    }
    float hv = db1[lane];
#pragma unroll
    for (int j = 0; j < 5; ++j) hv += z[j] * dw1[lane * 5 + j];
    hid_lds[nl][lane] = fmaxf(hv, 0.f);
    __syncthreads();

    if (lane < 20) {
        float acc = db2[lane];
#pragma unroll
        for (int k = 0; k < 32; ++k) acc += hid_lds[nl][k] * dw2[lane * 32 + k];
        out[OUT_RECON + n * 20 + lane] = acc;
    }
}

// ===== per-graph-pair kernel: 512 blocks x 512 threads (8 waves), 2 graphs =
// nt-split over 8 waves ({w, 8+w}, +16 on w0), ea staged in LDS,
// fc1 = 1 nt/wave, L1 = 1 col/thread.
__global__ __launch_bounds__(512) void graph_kernel(
    const float* __restrict__ x,   const float* __restrict__ ea,
    const float* __restrict__ partial,
    const float* __restrict__ W1E,
    const float* __restrict__ g1_We, const float* __restrict__ g1_ae,
    const float* __restrict__ g1_b,
    const unsigned short* __restrict__ WTEf2,
    const float* __restrict__ g2_We, const float* __restrict__ g2_ae,
    const float* __restrict__ g2_b,
    const unsigned short* __restrict__ WTEf3,
    const float* __restrict__ g3_We, const float* __restrict__ g3_ae,
    const float* __restrict__ g3_b,
    const unsigned short* __restrict__ FT1f,
    const float* __restrict__ fc1W, const float* __restrict__ fc1b,
    const float* __restrict__ fc2W, const float* __restrict__ fc2b,
    float* __restrict__ out)
{
    __shared__ char hsb[2][8192] __attribute__((aligned(16)));
    __shared__ float salsald[2][16][16];
    __shared__ unsigned short coefb[2][8][16][20] __attribute__((aligned(8)));
    __shared__ float sS[8];
    __shared__ float hs6[2][16][6];
    __shared__ float lash[2][8][3];
    __shared__ float hidn[16][132];
    __shared__ unsigned short gembb[2][256] __attribute__((aligned(8)));
    __shared__ float ealds[480];

    const int tid = threadIdx.x;
    const int g0 = blockIdx.x * 2;
    const int lane = tid & 63, w = tid >> 6;
    const int arow = lane & 15, kg = lane >> 4;

    // --- edge-attr mean (per-wave butterfly) ---
    float eamean;
    {
        float pv = partial[lane] + partial[lane + 64] + partial[lane + 128] + partial[lane + 192];
        pv += __shfl_xor(pv, 1);
        pv += __shfl_xor(pv, 2);
        pv += __shfl_xor(pv, 4);
        pv += __shfl_xor(pv, 8);
        pv += __shfl_xor(pv, 16);
        pv += __shfl_xor(pv, 32);
        eamean = pv * (1.f / (float)EDGES);
    }

    // --- stage inputs (+ ea tile: 480 contiguous floats for both graphs) ---
    if (tid < 192) {
        const int gg = tid / 96, t = tid % 96;
        hs6[gg][t / 6][t % 6] = x[((g0 + gg) * 16 + t / 6) * 29 + 20 + t % 6];
    } else if (tid < 240) {
        const int t = tid - 192, gg = t / 24, r = t % 24;
        lash[gg][r / 3][r % 3] = x[((g0 + gg) * 16 + r / 3) * 29 + 26 + r % 3];
    } else if (tid >= 248 && tid < 256) {
        const int h = tid - 248;
        float s = 0.f;
        for (int c = 0; c < 32; ++c) s += g1_We[h * 32 + c] * g1_ae[h * 32 + c];
        sS[h] = s;
    } else if (tid >= 256) {
        const int t = tid - 256;
        ealds[t] = ea[g0 * EPG + t];
        if (t < 224) ealds[t + 256] = ea[g0 * EPG + t + 256];
    }
    __syncthreads();

    // ===== L1: thread = (graph gg = tid>>8, col ht = tid&255) =====
    float colA[16];
    {
        const int gg = tid >> 8, ht = tid & 255;
#pragma unroll
        for (int i = 0; i < 16; ++i) colA[i] = 0.f;
#pragma unroll
        for (int k = 0; k < 6; ++k) {
            const float wa = W1E[k * 272 + ht];
#pragma unroll
            for (int i = 0; i < 16; ++i) colA[i] += hs6[gg][i][k] * wa;
        }
        if (ht < 16) {
            float colC[16];
#pragma unroll
            for (int i = 0; i < 16; ++i) colC[i] = 0.f;
#pragma unroll
            for (int k = 0; k < 6; ++k) {
                const float wc = W1E[k * 272 + 256 + ht];
#pragma unroll
                for (int i = 0; i < 16; ++i) colC[i] += hs6[gg][i][k] * wc;
            }
#pragma unroll
            for (int i = 0; i < 16; ++i) salsald[gg][i][ht] = colC[i];
        }
    }
    __syncthreads();

    // --- L1 softmax (no self loop): 256 rows on threads 0..255 ---
    if (tid < 256) {
        const int gg = tid >> 7, row = tid & 127;
        const int d = row >> 3, h = row & 7;
        const float S = sS[h];
        const float aldv = salsald[gg][d][8 + h];
        float alf[16];
        float m = -1e30f;
#pragma unroll
        for (int s = 0; s < 16; ++s) {
            float a;
            if (s == d) a = -1e30f;
            else {
                const int el = s * 15 + d - (d > s ? 1 : 0);
                a = lrelu02(salsald[gg][s][h] + aldv + ealds[gg * EPG + el] * S);
            }
            alf[s] = a;
            m = fmaxf(m, a);
        }
        float sum = 0.f;
#pragma unroll
        for (int s = 0; s < 16; ++s) { alf[s] = expf(alf[s] - m); sum += alf[s]; }
        const float r = 1.f / (sum + 1e-16f);
#pragma unroll
        for (int s = 0; s < 16; ++s) coefb[gg][h][d][s] = f2bf(alf[s] * r);
    }
    __syncthreads();

    // --- L1 aggregate from register column ---
    {
        const int gg = tid >> 8, c = tid & 255;
        const int h = c >> 5;
        const float b = g1_b[c];
#pragma unroll
        for (int d = 0; d < 16; ++d) {
            float v = b;
#pragma unroll
            for (int s4 = 0; s4 < 4; ++s4) {
                const bf16x4 cv = *(const bf16x4*)((const char*)&coefb[gg][0][0][0] + h * 640 + d * 40 + s4 * 8);
                v += bf2f((unsigned short)cv[0]) * colA[s4 * 4 + 0]
                   + bf2f((unsigned short)cv[1]) * colA[s4 * 4 + 1]
                   + bf2f((unsigned short)cv[2]) * colA[s4 * 4 + 2]
                   + bf2f((unsigned short)cv[3]) * colA[s4 * 4 + 3];
            }
            *(unsigned short*)(hsb[gg] + ((d * 512 + c * 2) ^ ((d & 7) << 4))) = f2bf(fmaxf(v, 0.f));
        }
    }
    __syncthreads();

    // ===== layers 2 and 3 =====
#pragma unroll 1
    for (int ly = 0; ly < 2; ++ly) {
        const unsigned short* WT = ly ? WTEf3 : WTEf2;
        const float* We_ = ly ? g3_We : g2_We;
        const float* ae_ = ly ? g3_ae : g2_ae;
        const float* bi_ = ly ? g3_b  : g2_b;

        if (tid < 8) {
            float s = 0.f;
            for (int c = 0; c < 32; ++c) s += We_[tid * 32 + c] * ae_[tid * 32 + c];
            sS[tid] = s;
        }

        // --- GEMM: wave w owns nt = {w, 8+w}; wave 0 also nt=16; 2 graphs ---
        f32x4 acc[3][2];
#pragma unroll
        for (int t = 0; t < 3; ++t) { acc[t][0] = (f32x4){0,0,0,0}; acc[t][1] = (f32x4){0,0,0,0}; }
        {
            const int aswz = (arow & 7) << 4;
            for (int kk = 0; kk < 8; ++kk) {
                bf16x8 afr[2];
#pragma unroll
                for (int gg = 0; gg < 2; ++gg) {
                    const int ab = arow * 512 + kk * 64 + kg * 8;
                    const bf16x4 alo = *(const bf16x4*)(hsb[gg] + (ab ^ aswz));
                    const bf16x4 ahi = *(const bf16x4*)(hsb[gg] + ((ab + 32) ^ aswz));
                    afr[gg] = (bf16x8){alo[0], alo[1], alo[2], alo[3],
                                       ahi[0], ahi[1], ahi[2], ahi[3]};
                }
#pragma unroll
                for (int t = 0; t < 2; ++t) {
                    const int nt = t * 8 + w;
                    const bf16x8 bfr = *(const bf16x8*)(WT + (size_t)((nt * 8 + kk) * 64 + lane) * 8);
                    acc[t][0] = __builtin_amdgcn_mfma_f32_16x16x32_bf16(afr[0], bfr, acc[t][0], 0, 0, 0);
                    acc[t][1] = __builtin_amdgcn_mfma_f32_16x16x32_bf16(afr[1], bfr, acc[t][1], 0, 0, 0);
                }
                if (w == 0) {
                    const bf16x8 bfr = *(const bf16x8*)(WT + (size_t)((16 * 8 + kk) * 64 + lane) * 8);
                    acc[2][0] = __builtin_amdgcn_mfma_f32_16x16x32_bf16(afr[0], bfr, acc[2][0], 0, 0, 0);
                    acc[2][1] = __builtin_amdgcn_mfma_f32_16x16x32_bf16(afr[1], bfr, acc[2][1], 0, 0, 0);
                }
            }
        }
        // nt==16 (wave 0) -> als/ald to LDS
        if (w == 0) {
#pragma unroll
            for (int gg = 0; gg < 2; ++gg)
#pragma unroll
                for (int r = 0; r < 4; ++r) salsald[gg][kg * 4 + r][arow] = acc[2][gg][r];
        }
        __syncthreads();

        // --- softmax: 256 rows on threads 0..255 ---
        if (tid < 256) {
            const int gg = tid >> 7, row = tid & 127;
            const int d = row >> 3, h = row & 7;
            const float S = sS[h];
            const float aldv = salsald[gg][d][8 + h];
            float alf[16];
            float m = -1e30f;
#pragma unroll
            for (int s = 0; s < 16; ++s) {
                float a;
                if (s == d) a = lrelu02(salsald[gg][s][h] + aldv + eamean * S);
                else {
                    const int el = s * 15 + d - (d > s ? 1 : 0);
                    a = lrelu02(salsald[gg][s][h] + aldv + ealds[gg * EPG + el] * S);
                }
                alf[s] = a;
                m = fmaxf(m, a);
            }
            float sum = 0.f;
#pragma unroll
            for (int s = 0; s < 16; ++s) { alf[s] = expf(alf[s] - m); sum += alf[s]; }
            const float r = 1.f / (sum + 1e-16f);
#pragma unroll
            for (int s = 0; s < 16; ++s) coefb[gg][h][d][s] = f2bf(alf[s] * r);
        }
        __syncthreads();

        // --- aggregate via MFMA from own GEMM regs: nt = {w, 8+w} ---
        {
#pragma unroll
            for (int t = 0; t < 2; ++t) {
                const int nt = t * 8 + w;
                const int h = nt >> 1;
                const int c2 = nt * 16 + arow;
#pragma unroll
                for (int gg = 0; gg < 2; ++gg) {
                    const bf16x4 alo = *(const bf16x4*)((const char*)&coefb[gg][0][0][0] + h * 640 + arow * 40 + kg * 8);
                    const bf16x8 afrag = (bf16x8){alo[0], alo[1], alo[2], alo[3], 0, 0, 0, 0};
                    const bf16x8 bfr = (bf16x8){
                        (short)f2bf(acc[t][gg][0]), (short)f2bf(acc[t][gg][1]),
                        (short)f2bf(acc[t][gg][2]), (short)f2bf(acc[t][gg][3]),
                        0, 0, 0, 0};
                    f32x4 hacc = __builtin_amdgcn_mfma_f32_16x16x32_bf16(
                                     afrag, bfr, (f32x4){0.f, 0.f, 0.f, 0.f}, 0, 0, 0);
                    const float b = bi_[c2];
                    float p = 0.f;
#pragma unroll
                    for (int r = 0; r < 4; ++r) {
                        const float hv = fmaxf(hacc[r] + b, 0.f);
                        p += hv;
                        const int d = kg * 4 + r;
                        *(unsigned short*)(hsb[gg] + ((d * 512 + c2 * 2) ^ ((d & 7) << 4))) = f2bf(hv);
                    }
                    if (ly == 1) {
                        p += __shfl_xor(p, 16);
                        p += __shfl_xor(p, 32);
                        if (kg == 0) gembb[gg][c2] = f2bf(p * (1.f / 16.f));
                    }
                }
            }
        }
        __syncthreads();
    }

    // ===== fc1 via MFMA: wave w owns nt = w (one 16-col tile) =====
    {
        f32x4 acc2 = (f32x4){0,0,0,0};
        const int agg = arow >> 3, alr = arow & 7;
        const int aswz = (alr & 7) << 4;
        for (int kk = 0; kk < 16; ++kk) {
            bf16x4 alo, ahi;
            if (kk < 8) {
                const int ab = alr * 512 + kk * 64 + kg * 8;
                alo = *(const bf16x4*)(hsb[agg] + (ab ^ aswz));
                ahi = *(const bf16x4*)(hsb[agg] + ((ab + 32) ^ aswz));
            } else {
                const char* gp = (const char*)&gembb[agg][0] + (kk - 8) * 64 + kg * 8;
                alo = *(const bf16x4*)(gp);
                ahi = *(const bf16x4*)(gp + 32);
            }
            const bf16x8 afrag = (bf16x8){alo[0], alo[1], alo[2], alo[3],
                                          ahi[0], ahi[1], ahi[2], ahi[3]};
            const bf16x8 bfr = *(const bf16x8*)(FT1f + (size_t)((w * 16 + kk) * 64 + lane) * 8);
            acc2 = __builtin_amdgcn_mfma_f32_16x16x32_bf16(afrag, bfr, acc2, 0, 0, 0);
        }
        {
            const int o = w * 16 + arow;
            const float wl0 = fc1W[o * 515 + 512];
            const float wl1 = fc1W[o * 515 + 513];
            const float wl2 = fc1W[o * 515 + 514];
            const float b   = fc1b[o];
#pragma unroll
            for (int r = 0; r < 4; ++r) {
                const int row = kg * 4 + r;
                const int gg = row >> 3, ag = row & 7;
                float v = acc2[r] + b
                        + lash[gg][ag][0] * wl0 + lash[gg][ag][1] * wl1 + lash[gg][ag][2] * wl2;
                hidn[row][o] = fmaxf(v, 0.f);
            }
        }
    }
    __syncthreads();

    // --- fc2 + output transforms (16 agents x 6) ---
    if (tid < 96) {
        const int a = tid / 6, j = tid % 6;
        const float* wr = &fc2W[j * 128];
        float acc = fc2b[j];
#pragma unroll
        for (int k = 0; k < 128; ++k) acc += wr[k] * hidn[a][k];
        const int gg = a >> 3, ag = a & 7;
        const int base = ((g0 + gg) * 8 + ag) * 3;
        if (j < 3) {
            const float lim = (j == 2) ? 3.1415927f : 1.0f;
            out[OUT_MEAN + base + j] = tanhf(acc) * lim;
        } else {
            const float sg = 1.f / (1.f + expf(-acc));
            out[OUT_STD + base + (j - 3)] = 0.01f + sg * (0.3f - 0.01f) + 1e-5f;
        }
    }
}

extern "C" void kernel_launch(void* const* d_in, const int* in_sizes, int n_in,
                              void* d_out, int out_size, void* d_ws, size_t ws_size,
                              hipStream_t stream)
{
    const float* x     = (const float*)d_in[0];
    const float* ea    = (const float*)d_in[2];
    const float* lc_w1 = (const float*)d_in[6];
    const float* lc_b1 = (const float*)d_in[7];
    const float* lc_w2 = (const float*)d_in[8];
    const float* lc_b2 = (const float*)d_in[9];
    const float* lc_wl = (const float*)d_in[10];
    const float* lc_bl = (const float*)d_in[11];
    const float* ld_w1 = (const float*)d_in[12];
    const float* ld_b1 = (const float*)d_in[13];
    const float* ld_w2 = (const float*)d_in[14];
    const float* ld_b2 = (const float*)d_in[15];
    const float* g1_W  = (const float*)d_in[16];
    const float* g1_as = (const float*)d_in[17];
    const float* g1_ad = (const float*)d_in[18];
    const float* g1_We = (const float*)d_in[19];
    const float* g1_ae = (const float*)d_in[20];
    const float* g1_b  = (const float*)d_in[21];
    const float* g2_W  = (const float*)d_in[22];
    const float* g2_as = (const float*)d_in[23];
    const float* g2_ad = (const float*)d_in[24];
    const float* g2_We = (const float*)d_in[25];
    const float* g2_ae = (const float*)d_in[26];
    const float* g2_b  = (const float*)d_in[27];
    const float* g3_W  = (const float*)d_in[28];
    const float* g3_as = (const float*)d_in[29];
    const float* g3_ad = (const float*)d_in[30];
    const float* g3_We = (const float*)d_in[31];
    const float* g3_ae = (const float*)d_in[32];
    const float* g3_b  = (const float*)d_in[33];
    const float* fc1_W = (const float*)d_in[34];
    const float* fc1_b = (const float*)d_in[35];
    const float* fc2_W = (const float*)d_in[36];
    const float* fc2_b = (const float*)d_in[37];

    float* out = (float*)d_out;
    unsigned short* WTEf2 = (unsigned short*)d_ws;        // 8704*8 bf16
    unsigned short* WTEf3 = WTEf2 + 8704 * 8;
    unsigned short* FT1f  = WTEf3 + 8704 * 8;             // 8192*8 bf16
    float* W1E    = (float*)(FT1f + 8192 * 8);            // 6*272 f32
    float* partial = W1E + 6 * 272;                       // 256 f32

    prep_kernel<<<2405, 256, 0, stream>>>(x, ea,
                                          g2_W, g2_as, g2_ad,
                                          g3_W, g3_as, g3_ad,
                                          g1_W, g1_as, g1_ad,
                                          fc1_W,
                                          lc_w1, lc_b1, lc_w2, lc_b2, lc_wl, lc_bl,
                                          ld_w1, ld_b1, ld_w2, ld_b2,
                                          WTEf2, WTEf3, FT1f, W1E, partial, out);

    graph_kernel<<<512, 512, 0, stream>>>(x, ea, partial,
                                          W1E, g1_We, g1_ae, g1_b,
                                          WTEf2, g2_We, g2_ae, g2_b,
                                          WTEf3, g3_We, g3_ae, g3_b,
                                          FT1f, fc1_W, fc1_b, fc2_W, fc2_b, out);
}